// Round 12
// baseline (6207.321 us; speedup 1.0000x reference)
//
#include <hip/hip_runtime.h>
#include <cstdint>
#include <cstddef>

namespace {
constexpr int T_ = 500, S_ = 32, B_ = 128, L_ = 64, R_ = 8;

__device__ __forceinline__ float rdlane(float v, int l) {
  return __int_as_float(__builtin_amdgcn_readlane(__float_as_int(v), l));
}
template<int CTRL, int RM>
__device__ __forceinline__ float dppadd(float v) {
  int t = __builtin_amdgcn_update_dpp(0, __float_as_int(v), CTRL, RM, 0xf, false);
  return v + __int_as_float(t);
}
// full 64-lane sum; total lands in lane 63 (VALU-only, no DS)
__device__ __forceinline__ float wredsum(float v) {
  v = dppadd<0x111, 0xf>(v);   // row_shr:1
  v = dppadd<0x112, 0xf>(v);   // row_shr:2
  v = dppadd<0x114, 0xf>(v);   // row_shr:4
  v = dppadd<0x118, 0xf>(v);   // row_shr:8
  v = dppadd<0x142, 0xa>(v);   // row_bcast:15 -> rows 1,3
  v = dppadd<0x143, 0xc>(v);   // row_bcast:31 -> rows 2,3
  return v;
}
__device__ __forceinline__ float wsum(float v) {  // all-lanes result (step0 only)
  v += __shfl_xor(v, 1);  v += __shfl_xor(v, 2);  v += __shfl_xor(v, 4);
  v += __shfl_xor(v, 8);  v += __shfl_xor(v, 16); v += __shfl_xor(v, 32);
  return v;
}
__device__ __forceinline__ void gload16(const float* g, float* l) {
  __builtin_amdgcn_global_load_lds((const __attribute__((address_space(1))) uint32_t*)g,
                                   (__attribute__((address_space(3))) uint32_t*)l,
                                   16, 0, 0);
}
// barrier that drains LDS ops but lets global loads/stores ride (vmcnt untouched)
__device__ __forceinline__ void bar_lgkm() {
  asm volatile("s_waitcnt lgkmcnt(0)\n\ts_barrier" ::: "memory");
}
}  // namespace

// One block per batch element b. 512 threads = 8 waves, 4 ensemble rows/wave.
// R11 base (mkm identity + M8-symmetry fold) plus:
//  - Mc_s chunk-rotated layout: logical col-chunk j lives at physical chunk
//    ((j + (lam>>3)) & 7) of the lane's row -> scalar writes AND b128 reads
//    are bank-conflict-free while multiply partners stay wave-broadcast.
//  - mkm computed ONCE (wave 3) and published via mkm_s[64][8]; other waves
//    read 2 x b128 (contiguous 16B/lane, canonical conflict-free pattern).
__global__ __launch_bounds__(512, 1) void nlf_kernel(
    const float* __restrict__ m0p, const float* __restrict__ q0p,
    const float* __restrict__ qp,  const float* __restrict__ kp,
    const float* __restrict__ Kp,  const float* __restrict__ Ap,
    const float* __restrict__ wp0p, const float* __restrict__ wf0p,
    const float* __restrict__ wp1p, const float* __restrict__ wp2p,
    const float* __restrict__ wfp,  float* __restrict__ outp)
{
  __shared__ __align__(16) float z_s[S_*68];      // carry z' (z - mf)
  __shared__ __align__(16) float Mc_s[L_*36];     // M_c[l][s], chunk-rotated
  __shared__ __align__(16) float uni[8*68];       // mp partial sums
  __shared__ __align__(16) float wp1b[2][S_*S_];
  __shared__ __align__(16) float wp2b[2][S_*L_];
  __shared__ __align__(16) float wf_s[S_*R_];
  __shared__ __align__(16) float Kt_s[L_*R_];
  __shared__ __align__(16) float v1t_s[S_*R_];
  __shared__ __align__(16) float KM_s[S_*R_];     // [s*8+r] = (Mc^T K)[s][r]
  __shared__ __align__(16) float mkm_s[L_*R_];    // [lam*8+r] = (Mc MKM row)
  __shared__ __align__(16) float M8_s[64];
  __shared__ __align__(16) float C8_s[64];
  __shared__ __align__(16) float tk_s[S_];        // Mc^T k_t
  __shared__ __align__(16) float t8_s[8];         // K^T u (wave0 P3 -> P4)
  __shared__ __align__(16) float mf_s[L_];
  __shared__ __align__(16) float qv_s[L_];
  __shared__ __align__(16) float q0v_s[L_];

  const int tid = threadIdx.x;
  const int lam = tid & 63;
  const int w   = tid >> 6;
  const int b   = blockIdx.x;
  const int rot = lam >> 3;          // Mc_s chunk rotation for this lane

  float Areg[64];
#pragma unroll
  for (int j4 = 0; j4 < 16; ++j4) {
    float4 a4 = *(const float4*)(Ap + (size_t)lam*64 + j4*4);
    Areg[4*j4+0]=a4.x; Areg[4*j4+1]=a4.y; Areg[4*j4+2]=a4.z; Areg[4*j4+3]=a4.w;
  }
  const float q_r  = qp[lam];
  const float qs_r = sqrtf(q_r);
  const float q0_r = q0p[lam];
  const float m0_r = m0p[lam];
  if (tid < 64) { qv_s[tid] = q_r; q0v_s[tid] = q0_r; }

  float Kreg[8];
  {
    const float* kb = Kp + (size_t)b*(L_*R_) + lam*R_;
    float4 ka = *(const float4*)kb, kb4 = *(const float4*)(kb+4);
    Kreg[0]=ka.x;Kreg[1]=ka.y;Kreg[2]=ka.z;Kreg[3]=ka.w;
    Kreg[4]=kb4.x;Kreg[5]=kb4.y;Kreg[6]=kb4.z;Kreg[7]=kb4.w;
  }
  float kt_r = kp[(size_t)b*L_ + lam];

  // ---- prologue async loads ----
  if (w == 0) {                       // wp1[0] -> wp1b[1]
#pragma unroll
    for (int m = 0; m < 4; ++m) {
      int f = m*256 + lam*4, s = f >> 5, c = f & 31;
      gload16(wp1p + ((size_t)s*B_ + b)*S_ + c, &wp1b[1][f]);
    }
  } else if (w == 1 || w == 2) {      // wp2[0] -> wp2b[1]
#pragma unroll
    for (int m = 0; m < 4; ++m) {
      int f = (w-1)*1024 + m*256 + lam*4, s = f >> 6, c = f & 63;
      gload16(wp2p + ((size_t)s*B_ + b)*L_ + c, &wp2b[1][f]);
    }
  } else if (w == 3) {                // wf0 -> wf_s ; K[0] -> Kt_s
    { int f = lam*4, s = f >> 3, c = f & 7;
      gload16(wf0p + ((size_t)s*B_ + b)*R_ + c, &wf_s[f]); }
#pragma unroll
    for (int m = 0; m < 2; ++m) {
      int f = m*256 + lam*4;
      gload16(Kp + (size_t)b*(L_*R_) + f, &Kt_s[f]);
    }
  } else if (w == 4 || w == 5) {      // w_p0 -> wp2b[0]
#pragma unroll
    for (int m = 0; m < 4; ++m) {
      int f = (w-4)*1024 + m*256 + lam*4, s = f >> 6, c = f & 63;
      gload16(wp0p + ((size_t)s*B_ + b)*L_ + c, &wp2b[0][f]);
    }
  }
  __syncthreads();

  // 8x8 SPD: C8_s -> M8_s = inv(C8) via in-register Cholesky (rows in lanes 0-7)
  auto chol8M8 = [&]() {
    const int i8 = lam & 7;
    float c8[8], rd8 = 0.0f;
#pragma unroll
    for (int k = 0; k < 8; ++k) c8[k] = C8_s[i8*8 + k];
#pragma unroll
    for (int j = 0; j < 8; ++j) {
      float dj = rdlane(c8[j], j);
      float rinv = rsqrtf(dj);
      if (i8 == j) rd8 = rinv;
      c8[j] *= rinv;
#pragma unroll
      for (int k = j+1; k < 8; ++k)
        c8[k] = fmaf(-rdlane(c8[j], k), c8[j], c8[k]);
    }
    float w8[8];
#pragma unroll
    for (int i = 0; i < 8; ++i) {
      float sacc = (i == i8) ? 1.0f : 0.0f;
#pragma unroll
      for (int k = 0; k < i; ++k)
        sacc = fmaf(-rdlane(c8[k], i), w8[k], sacc);
      w8[i] = sacc * rdlane(rd8, i);
    }
#pragma unroll
    for (int i = 0; i < 8; ++i) {
      float msum = 0.0f;
#pragma unroll
      for (int k = 0; k < 8; ++k)
        msum = fmaf(rdlane(w8[k], i), w8[k], msum);
      if (lam < 8) M8_s[i*8 + lam] = msum;
    }
  };

  // ================= step 0 =================
  {
    const float Pp = q0_r;
    const float h0 = m0_r / Pp + kt_r;
    if (w == 0) {
      const int r1 = lam >> 3, r2 = lam & 7;
      float acc = 0.0f;
#pragma unroll 4
      for (int l = 0; l < 64; ++l)
        acc = fmaf(Kt_s[l*8 + r1] * q0v_s[l], Kt_s[l*8 + r2], acc);
      C8_s[lam] = acc + (r1 == r2 ? 1.0f : 0.0f);
      chol8M8();
      float t8[8];
#pragma unroll
      for (int r = 0; r < 8; ++r) t8[r] = wsum(Pp * Kreg[r] * h0);
      float acc2 = 0.0f;
#pragma unroll
      for (int r1i = 0; r1i < 8; ++r1i) {
        float4 ma = *(const float4*)&M8_s[r1i*8];
        float4 mb = *(const float4*)&M8_s[r1i*8+4];
        float y = ma.x*t8[0]+ma.y*t8[1]+ma.z*t8[2]+ma.w*t8[3]
                + mb.x*t8[4]+mb.y*t8[5]+mb.z*t8[6]+mb.w*t8[7];
        acc2 = fmaf(Kreg[r1i], y, acc2);
      }
      float m0f = Pp*h0 - Pp*acc2;
      mf_s[lam] = m0f;
      outp[(size_t)b*L_ + lam] = m0f;
    }
    __syncthreads();

    const float qs0 = sqrtf(q0_r);
#pragma unroll
    for (int i = 0; i < 4; ++i) {
      const int s = 4*w + i;
      float zp = qs0 * wp2b[0][s*64 + lam];
      float v1[8];
#pragma unroll
      for (int r = 0; r < 8; ++r)
        v1[r] = wsum(Kreg[r] * zp) + wf_s[s*8 + r];
      float acc = 0.0f;
#pragma unroll
      for (int r1i = 0; r1i < 8; ++r1i) {
        float4 ma = *(const float4*)&M8_s[r1i*8];
        float4 mb = *(const float4*)&M8_s[r1i*8+4];
        float y = ma.x*v1[0]+ma.y*v1[1]+ma.z*v1[2]+ma.w*v1[3]
                + mb.x*v1[4]+mb.y*v1[5]+mb.z*v1[6]+mb.w*v1[7];
        acc = fmaf(Kreg[r1i], y, acc);
      }
      z_s[s*68 + lam] = zp - Pp*acc;   // z' excludes m_f (added in next dyn)
    }
  }
  __syncthreads();

  // ================= steps 1..T-1 =================
  for (int t = 1; t < T_; ++t) {
    const int cb = t & 1, nb = cb ^ 1;

    // per-lane K/k reload (global; hidden under P1, used from P2 on)
    {
      const float* kb = Kp + ((size_t)t*B_ + b)*(L_*R_) + lam*R_;
      float4 ka = *(const float4*)kb, kb4 = *(const float4*)(kb+4);
      Kreg[0]=ka.x;Kreg[1]=ka.y;Kreg[2]=ka.z;Kreg[3]=ka.w;
      Kreg[4]=kb4.x;Kreg[5]=kb4.y;Kreg[6]=kb4.z;Kreg[7]=kb4.w;
      kt_r = kp[((size_t)t*B_ + b)*L_ + lam];
    }

    // ---- P1: dyn on z = z' + mf (rows via conflict-free b128 broadcasts) ----
    float dmf = 0.0f;
#pragma unroll
    for (int j4 = 0; j4 < 16; ++j4) {
      float4 m4 = *(const float4*)&mf_s[4*j4];
      dmf = fmaf(m4.x, Areg[4*j4+0], dmf);
      dmf = fmaf(m4.y, Areg[4*j4+1], dmf);
      dmf = fmaf(m4.z, Areg[4*j4+2], dmf);
      dmf = fmaf(m4.w, Areg[4*j4+3], dmf);
    }
    const float mfl = mf_s[lam];
    float zn[4];
#pragma unroll
    for (int i = 0; i < 4; ++i) {
      const int s = 4*w + i;
      float a0=0,a1=0,a2=0,a3=0;
#pragma unroll
      for (int j4 = 0; j4 < 16; ++j4) {
        float4 zb = *(const float4*)&z_s[s*68 + 4*j4];
        a0 = fmaf(zb.x, Areg[4*j4+0], a0);
        a1 = fmaf(zb.y, Areg[4*j4+1], a1);
        a2 = fmaf(zb.z, Areg[4*j4+2], a2);
        a3 = fmaf(zb.w, Areg[4*j4+3], a3);
      }
      float x = ((a0+a1)+(a2+a3)) + dmf;
      float e = __expf(2.0f*x);
      float tnh = 1.0f - 2.0f/(e + 1.0f);
      zn[i] = (z_s[s*68 + lam] + mfl) + 0.1f*tnh;
    }
    uni[w*68 + lam] = zn[0]+zn[1]+zn[2]+zn[3];
    bar_lgkm();  // B1

    // ---- P0: async prefetch; drains at B2 (syncthreads) ----
    if (w == 0) {
      if (t < T_-1) {
#pragma unroll
        for (int m = 0; m < 4; ++m) {
          int f = m*256 + lam*4, s = f >> 5, c = f & 31;
          gload16(wp1p + (((size_t)t*S_ + s)*B_ + b)*S_ + c, &wp1b[nb][f]);
        }
      }
    } else if (w == 1 || w == 2) {
      if (t < T_-1) {
#pragma unroll
        for (int m = 0; m < 4; ++m) {
          int f = (w-1)*1024 + m*256 + lam*4, s = f >> 6, c = f & 63;
          gload16(wp2p + (((size_t)t*S_ + s)*B_ + b)*L_ + c, &wp2b[nb][f]);
        }
      }
    } else if (w == 3) {
      { int f = lam*4, s = f >> 3, c = f & 7;
        gload16(wfp + (((size_t)(t-1)*S_ + s)*B_ + b)*R_ + c, &wf_s[f]); }
#pragma unroll
      for (int m = 0; m < 2; ++m) {
        int f = m*256 + lam*4;
        gload16(Kp + ((size_t)t*B_ + b)*(L_*R_) + f, &Kt_s[f]);
      }
    }

    // ---- P2: m_p, M_c (rotated store), KM = Mc^T K, tk = Mc^T k_t ----
    float mp = 0.0f;
#pragma unroll
    for (int ww = 0; ww < 8; ++ww) mp += uni[ww*68 + lam];
    mp *= 0.03125f;
    {
      const int wchunk = lam*36 + 4*((w + rot) & 7);   // physical chunk for s=4w..4w+3
#pragma unroll
      for (int i = 0; i < 4; ++i) {
        const int s = 4*w + i;
        float mcv = (zn[i] - mp) * 0.17677669529663689f;
        Mc_s[wchunk + i] = mcv;
        float tkv = wredsum(mcv * kt_r);
        float kmv[8];
#pragma unroll
        for (int r = 0; r < 8; ++r) kmv[r] = wredsum(mcv * Kreg[r]);
        if (lam == 63) {
          tk_s[s] = tkv;
          *(float4*)&KM_s[s*8]   = make_float4(kmv[0],kmv[1],kmv[2],kmv[3]);
          *(float4*)&KM_s[s*8+4] = make_float4(kmv[4],kmv[5],kmv[6],kmv[7]);
        }
      }
    }
    __syncthreads();  // B2 (full: drains prefetch vmcnt)

    // ---- P3: zprows + wave0 {u, t8 -> LDS} + wave1 {C8, M8} + wave3 {mkm} ----
    float zloc[4];
    float u_r = 0.0f;
#pragma unroll
    for (int i = 0; i < 4; ++i) {
      const int s = 4*w + i;
      float acc = 0.0f;
#pragma unroll
      for (int j = 0; j < 8; ++j) {
        float4 mc4 = *(const float4*)&Mc_s[lam*36 + 4*((j + rot) & 7)];
        float4 wb  = *(const float4*)&wp1b[cb][s*32 + 4*j];
        acc = fmaf(mc4.x, wb.x, acc);
        acc = fmaf(mc4.y, wb.y, acc);
        acc = fmaf(mc4.z, wb.z, acc);
        acc = fmaf(mc4.w, wb.w, acc);
      }
      float zp = acc + qs_r * wp2b[cb][s*64 + lam];
      zloc[i] = zp;
      float vv[8];
#pragma unroll
      for (int r = 0; r < 8; ++r) vv[r] = wredsum(Kreg[r] * zp);
      if (lam == 63) {
        float4 wfa = *(const float4*)&wf_s[s*8];
        float4 wfb = *(const float4*)&wf_s[s*8+4];
        *(float4*)&v1t_s[s*8]   = make_float4(vv[0]+wfa.x, vv[1]+wfa.y,
                                              vv[2]+wfa.z, vv[3]+wfa.w);
        *(float4*)&v1t_s[s*8+4] = make_float4(vv[4]+wfb.x, vv[5]+wfb.y,
                                              vv[6]+wfb.z, vv[7]+wfb.w);
      }
    }
    if (w == 0) {
      // u = m_p + Mc tk + q k_t (Woodbury); t8 = K^T u -> LDS
      float mctk = 0.0f;
#pragma unroll
      for (int j = 0; j < 8; ++j) {
        float4 mc4 = *(const float4*)&Mc_s[lam*36 + 4*((j + rot) & 7)];
        float4 tb  = *(const float4*)&tk_s[4*j];
        mctk = fmaf(mc4.x, tb.x, mctk);
        mctk = fmaf(mc4.y, tb.y, mctk);
        mctk = fmaf(mc4.z, tb.z, mctk);
        mctk = fmaf(mc4.w, tb.w, mctk);
      }
      u_r = mp + mctk + q_r * kt_r;
      float vv[8];
#pragma unroll
      for (int r = 0; r < 8; ++r) vv[r] = wredsum(Kreg[r] * u_r);
      if (lam == 63) {
        *(float4*)&t8_s[0] = make_float4(vv[0],vv[1],vv[2],vv[3]);
        *(float4*)&t8_s[4] = make_float4(vv[4],vv[5],vv[6],vv[7]);
      }
    } else if (w == 1) {
      const int r1 = lam >> 3, r2 = lam & 7;
      float acc = 0.0f;
#pragma unroll 4
      for (int s = 0; s < 32; ++s)
        acc = fmaf(KM_s[s*8 + r1], KM_s[s*8 + r2], acc);
#pragma unroll 4
      for (int l = 0; l < 64; ++l)
        acc = fmaf(Kt_s[l*8 + r1] * qv_s[l], Kt_s[l*8 + r2], acc);
      C8_s[lam] = acc + (r1 == r2 ? 1.0f : 0.0f);
      chol8M8();
    } else if (w == 3) {
      // mkm[r] = sum_s2 Mc[lam][s2]*KM[s2][r] -- computed ONCE, published
      float mkm[8];
#pragma unroll
      for (int r = 0; r < 8; ++r) mkm[r] = 0.0f;
#pragma unroll
      for (int j = 0; j < 8; ++j) {
        float4 mc4 = *(const float4*)&Mc_s[lam*36 + 4*((j + rot) & 7)];
#pragma unroll
        for (int ii = 0; ii < 4; ++ii) {
          const float mcl = (ii==0)?mc4.x:(ii==1)?mc4.y:(ii==2)?mc4.z:mc4.w;
          float4 ka = *(const float4*)&KM_s[(4*j+ii)*8];
          float4 kb = *(const float4*)&KM_s[(4*j+ii)*8+4];
          mkm[0] = fmaf(mcl, ka.x, mkm[0]);
          mkm[1] = fmaf(mcl, ka.y, mkm[1]);
          mkm[2] = fmaf(mcl, ka.z, mkm[2]);
          mkm[3] = fmaf(mcl, ka.w, mkm[3]);
          mkm[4] = fmaf(mcl, kb.x, mkm[4]);
          mkm[5] = fmaf(mcl, kb.y, mkm[5]);
          mkm[6] = fmaf(mcl, kb.z, mkm[6]);
          mkm[7] = fmaf(mcl, kb.w, mkm[7]);
        }
      }
      *(float4*)&mkm_s[lam*8]   = make_float4(mkm[0],mkm[1],mkm[2],mkm[3]);
      *(float4*)&mkm_s[lam*8+4] = make_float4(mkm[4],mkm[5],mkm[6],mkm[7]);
    }
    bar_lgkm();  // B3 (M8_s, v1t_s, t8_s, mkm_s visible)

    // ---- P4: fold M8 once per lane (symmetric): kM8 = M8 K, mkmM8 = M8 mkm ----
    float4 mk_a = *(const float4*)&mkm_s[lam*8];
    float4 mk_b = *(const float4*)&mkm_s[lam*8+4];
    const float mkmv[8] = {mk_a.x, mk_a.y, mk_a.z, mk_a.w,
                           mk_b.x, mk_b.y, mk_b.z, mk_b.w};
    float kM8[8], mkmM8[8];
#pragma unroll
    for (int j = 0; j < 8; ++j) { kM8[j] = 0.0f; mkmM8[j] = 0.0f; }
#pragma unroll
    for (int r = 0; r < 8; ++r) {
      float4 ma = *(const float4*)&M8_s[r*8];
      float4 mb = *(const float4*)&M8_s[r*8+4];
      const float kr = Kreg[r], mr = mkmv[r];
      kM8[0] = fmaf(kr, ma.x, kM8[0]);   mkmM8[0] = fmaf(mr, ma.x, mkmM8[0]);
      kM8[1] = fmaf(kr, ma.y, kM8[1]);   mkmM8[1] = fmaf(mr, ma.y, mkmM8[1]);
      kM8[2] = fmaf(kr, ma.z, kM8[2]);   mkmM8[2] = fmaf(mr, ma.z, mkmM8[2]);
      kM8[3] = fmaf(kr, ma.w, kM8[3]);   mkmM8[3] = fmaf(mr, ma.w, mkmM8[3]);
      kM8[4] = fmaf(kr, mb.x, kM8[4]);   mkmM8[4] = fmaf(mr, mb.x, mkmM8[4]);
      kM8[5] = fmaf(kr, mb.y, kM8[5]);   mkmM8[5] = fmaf(mr, mb.y, mkmM8[5]);
      kM8[6] = fmaf(kr, mb.z, kM8[6]);   mkmM8[6] = fmaf(mr, mb.z, mkmM8[6]);
      kM8[7] = fmaf(kr, mb.w, kM8[7]);   mkmM8[7] = fmaf(mr, mb.w, mkmM8[7]);
    }
    // per row: g = kM8 . v1t, corr = mkmM8 . v1t  (2 b128 + 16 FMA)
#pragma unroll
    for (int i = 0; i < 4; ++i) {
      const int s = 4*w + i;
      float4 va = *(const float4*)&v1t_s[s*8];
      float4 vb = *(const float4*)&v1t_s[s*8+4];
      float g    = kM8[0]*va.x + kM8[1]*va.y + kM8[2]*va.z + kM8[3]*va.w
                 + kM8[4]*vb.x + kM8[5]*vb.y + kM8[6]*vb.z + kM8[7]*vb.w;
      float corr = mkmM8[0]*va.x + mkmM8[1]*va.y + mkmM8[2]*va.z + mkmM8[3]*va.w
                 + mkmM8[4]*vb.x + mkmM8[5]*vb.y + mkmM8[6]*vb.z + mkmM8[7]*vb.w;
      z_s[s*68 + lam] = zloc[i] - corr - q_r*g;   // z' (mf added next dyn)
    }
    if (w == 0) {   // mf tail: t8 from LDS; mf = u - mkmM8.t8 - q*(kM8.t8)
      float4 ta = *(const float4*)&t8_s[0];
      float4 tb = *(const float4*)&t8_s[4];
      float g    = kM8[0]*ta.x + kM8[1]*ta.y + kM8[2]*ta.z + kM8[3]*ta.w
                 + kM8[4]*tb.x + kM8[5]*tb.y + kM8[6]*tb.z + kM8[7]*tb.w;
      float corr = mkmM8[0]*ta.x + mkmM8[1]*ta.y + mkmM8[2]*ta.z + mkmM8[3]*ta.w
                 + mkmM8[4]*tb.x + mkmM8[5]*tb.y + mkmM8[6]*tb.z + mkmM8[7]*tb.w;
      const float mf_r = u_r - corr - q_r*g;
      mf_s[lam] = mf_r;
      outp[((size_t)t*B_ + b)*L_ + lam] = mf_r;
    }
    bar_lgkm();  // B4 (mf_s, z_s visible for next P1)
  }
}

extern "C" void kernel_launch(void* const* d_in, const int* in_sizes, int n_in,
                              void* d_out, int out_size, void* d_ws, size_t ws_size,
                              hipStream_t stream) {
  (void)in_sizes; (void)n_in; (void)out_size; (void)d_ws; (void)ws_size;
  nlf_kernel<<<dim3(B_), dim3(512), 0, stream>>>(
      (const float*)d_in[0], (const float*)d_in[1], (const float*)d_in[2],
      (const float*)d_in[3], (const float*)d_in[4], (const float*)d_in[5],
      (const float*)d_in[6], (const float*)d_in[7], (const float*)d_in[8],
      (const float*)d_in[9], (const float*)d_in[10], (float*)d_out);
}

// Round 13
// 4734.848 us; speedup vs baseline: 1.3110x; 1.3110x over previous
//
#include <hip/hip_runtime.h>
#include <hip/hip_bf16.h>
#include <cstdint>
#include <cstddef>

namespace {
constexpr int T_ = 500, S_ = 32, B_ = 128, L_ = 64, R_ = 8;

typedef __attribute__((ext_vector_type(8))) short short8;
typedef __attribute__((ext_vector_type(4))) float f32x4;

__device__ __forceinline__ float rdlane(float v, int l) {
  return __int_as_float(__builtin_amdgcn_readlane(__float_as_int(v), l));
}
template<int CTRL, int RM>
__device__ __forceinline__ float dppadd(float v) {
  int t = __builtin_amdgcn_update_dpp(0, __float_as_int(v), CTRL, RM, 0xf, false);
  return v + __int_as_float(t);
}
// full 64-lane sum; total lands in lane 63 (VALU-only, no DS)
__device__ __forceinline__ float wredsum(float v) {
  v = dppadd<0x111, 0xf>(v);   // row_shr:1
  v = dppadd<0x112, 0xf>(v);   // row_shr:2
  v = dppadd<0x114, 0xf>(v);   // row_shr:4
  v = dppadd<0x118, 0xf>(v);   // row_shr:8
  v = dppadd<0x142, 0xa>(v);   // row_bcast:15 -> rows 1,3
  v = dppadd<0x143, 0xc>(v);   // row_bcast:31 -> rows 2,3
  return v;
}
__device__ __forceinline__ float wsum(float v) {  // all-lanes result (step0 only)
  v += __shfl_xor(v, 1);  v += __shfl_xor(v, 2);  v += __shfl_xor(v, 4);
  v += __shfl_xor(v, 8);  v += __shfl_xor(v, 16); v += __shfl_xor(v, 32);
  return v;
}
__device__ __forceinline__ void gload16(const float* g, float* l) {
  __builtin_amdgcn_global_load_lds((const __attribute__((address_space(1))) uint32_t*)g,
                                   (__attribute__((address_space(3))) uint32_t*)l,
                                   16, 0, 0);
}
// barrier that drains LDS ops but lets global loads/stores ride (vmcnt untouched)
__device__ __forceinline__ void bar_lgkm() {
  asm volatile("s_waitcnt lgkmcnt(0)\n\ts_barrier" ::: "memory");
}
}  // namespace

// One block per batch element b. 512 threads = 8 waves, 4 ensemble rows/wave.
// R11 base (mkm identity + M8-symmetry fold, stride-36 Mc, per-wave mkm) plus
// MFMA-P1: dyn matvec X = (z'+mf) @ A^T on the matrix pipe via
// mfma_f32_16x16x32_bf16 with split-bf16 (hi+lo) operands (~fp32 accuracy).
// Wave w -> output tile (m = w>>2 over s, n = w&3 over l_out); K=64 in 2 steps.
// A^T fragments precomputed in registers (replaces Areg[64]: -48 VGPRs).
__global__ __launch_bounds__(512, 1) void nlf_kernel(
    const float* __restrict__ m0p, const float* __restrict__ q0p,
    const float* __restrict__ qp,  const float* __restrict__ kp,
    const float* __restrict__ Kp,  const float* __restrict__ Ap,
    const float* __restrict__ wp0p, const float* __restrict__ wf0p,
    const float* __restrict__ wp1p, const float* __restrict__ wp2p,
    const float* __restrict__ wfp,  float* __restrict__ outp)
{
  __shared__ __align__(16) float z_s[S_*68];      // carry z' (z - mf)
  __shared__ __align__(16) float zn_s[S_*68];     // dyn output zn
  __shared__ __align__(16) float Mc_s[L_*36];     // M_c[l][s], 16B-aligned rows
  __shared__ __align__(16) float uni[8*68];       // mp partials (mpp rows 0-7)
  __shared__ __align__(16) float wp1b[2][S_*S_];
  __shared__ __align__(16) float wp2b[2][S_*L_];
  __shared__ __align__(16) float wf_s[S_*R_];
  __shared__ __align__(16) float Kt_s[L_*R_];
  __shared__ __align__(16) float v1t_s[S_*R_];
  __shared__ __align__(16) float KM_s[S_*R_];     // [s*8+r] = (Mc^T K)[s][r]
  __shared__ __align__(16) float M8_s[64];
  __shared__ __align__(16) float C8_s[64];
  __shared__ __align__(16) float tk_s[S_];        // Mc^T k_t
  __shared__ __align__(16) float t8_s[8];         // K^T u (wave0 P3 -> P4)
  __shared__ __align__(16) float mf_s[L_];
  __shared__ __align__(16) float qv_s[L_];
  __shared__ __align__(16) float q0v_s[L_];

  const int tid = threadIdx.x;
  const int lam = tid & 63;
  const int w   = tid >> 6;
  const int b   = blockIdx.x;
  const int mtl = w >> 2, ntl = w & 3;      // MFMA tile coords
  const int cc  = lam & 15, gg = lam >> 4;  // MFMA lane coords

  const float q_r  = qp[lam];
  const float qs_r = sqrtf(q_r);
  const float q0_r = q0p[lam];
  const float m0_r = m0p[lam];
  if (tid < 64) { qv_s[tid] = q_r; q0v_s[tid] = q0_r; }

  // ---- A^T fragments (static): B-op lane holds A[n*16+cc][kk*32+gg*8+j] ----
  short8 Bh[2], Bl[2];
  {
    const float* arow = Ap + (size_t)(ntl*16 + cc)*64;
#pragma unroll
    for (int kk = 0; kk < 2; ++kk) {
      const int l0 = kk*32 + gg*8;
      float4 a4 = *(const float4*)(arow + l0);
      float4 b4 = *(const float4*)(arow + l0 + 4);
      float a8[8] = {a4.x,a4.y,a4.z,a4.w,b4.x,b4.y,b4.z,b4.w};
#pragma unroll
      for (int j = 0; j < 8; ++j) {
        __hip_bfloat16 hb = __float2bfloat16(a8[j]);
        Bh[kk][j] = __builtin_bit_cast(short, hb);
        float hf = __bfloat162float(hb);
        __hip_bfloat16 lb = __float2bfloat16(a8[j] - hf);
        Bl[kk][j] = __builtin_bit_cast(short, lb);
      }
    }
  }

  float Kreg[8];
  {
    const float* kb = Kp + (size_t)b*(L_*R_) + lam*R_;
    float4 ka = *(const float4*)kb, kb4 = *(const float4*)(kb+4);
    Kreg[0]=ka.x;Kreg[1]=ka.y;Kreg[2]=ka.z;Kreg[3]=ka.w;
    Kreg[4]=kb4.x;Kreg[5]=kb4.y;Kreg[6]=kb4.z;Kreg[7]=kb4.w;
  }
  float kt_r = kp[(size_t)b*L_ + lam];

  // ---- prologue async loads ----
  if (w == 0) {                       // wp1[0] -> wp1b[1]
#pragma unroll
    for (int m = 0; m < 4; ++m) {
      int f = m*256 + lam*4, s = f >> 5, c = f & 31;
      gload16(wp1p + ((size_t)s*B_ + b)*S_ + c, &wp1b[1][f]);
    }
  } else if (w == 1 || w == 2) {      // wp2[0] -> wp2b[1]
#pragma unroll
    for (int m = 0; m < 4; ++m) {
      int f = (w-1)*1024 + m*256 + lam*4, s = f >> 6, c = f & 63;
      gload16(wp2p + ((size_t)s*B_ + b)*L_ + c, &wp2b[1][f]);
    }
  } else if (w == 3) {                // wf0 -> wf_s ; K[0] -> Kt_s
    { int f = lam*4, s = f >> 3, c = f & 7;
      gload16(wf0p + ((size_t)s*B_ + b)*R_ + c, &wf_s[f]); }
#pragma unroll
    for (int m = 0; m < 2; ++m) {
      int f = m*256 + lam*4;
      gload16(Kp + (size_t)b*(L_*R_) + f, &Kt_s[f]);
    }
  } else if (w == 4 || w == 5) {      // w_p0 -> wp2b[0]
#pragma unroll
    for (int m = 0; m < 4; ++m) {
      int f = (w-4)*1024 + m*256 + lam*4, s = f >> 6, c = f & 63;
      gload16(wp0p + ((size_t)s*B_ + b)*L_ + c, &wp2b[0][f]);
    }
  }
  __syncthreads();

  // 8x8 SPD: C8_s -> M8_s = inv(C8) via in-register Cholesky (rows in lanes 0-7)
  auto chol8M8 = [&]() {
    const int i8 = lam & 7;
    float c8[8], rd8 = 0.0f;
#pragma unroll
    for (int k = 0; k < 8; ++k) c8[k] = C8_s[i8*8 + k];
#pragma unroll
    for (int j = 0; j < 8; ++j) {
      float dj = rdlane(c8[j], j);
      float rinv = rsqrtf(dj);
      if (i8 == j) rd8 = rinv;
      c8[j] *= rinv;
#pragma unroll
      for (int k = j+1; k < 8; ++k)
        c8[k] = fmaf(-rdlane(c8[j], k), c8[j], c8[k]);
    }
    float w8[8];
#pragma unroll
    for (int i = 0; i < 8; ++i) {
      float sacc = (i == i8) ? 1.0f : 0.0f;
#pragma unroll
      for (int k = 0; k < i; ++k)
        sacc = fmaf(-rdlane(c8[k], i), w8[k], sacc);
      w8[i] = sacc * rdlane(rd8, i);
    }
#pragma unroll
    for (int i = 0; i < 8; ++i) {
      float msum = 0.0f;
#pragma unroll
      for (int k = 0; k < 8; ++k)
        msum = fmaf(rdlane(w8[k], i), w8[k], msum);
      if (lam < 8) M8_s[i*8 + lam] = msum;
    }
  };

  // ================= step 0 =================
  {
    const float Pp = q0_r;
    const float h0 = m0_r / Pp + kt_r;
    if (w == 0) {
      const int r1 = lam >> 3, r2 = lam & 7;
      float acc = 0.0f;
#pragma unroll 4
      for (int l = 0; l < 64; ++l)
        acc = fmaf(Kt_s[l*8 + r1] * q0v_s[l], Kt_s[l*8 + r2], acc);
      C8_s[lam] = acc + (r1 == r2 ? 1.0f : 0.0f);
      chol8M8();
      float t8[8];
#pragma unroll
      for (int r = 0; r < 8; ++r) t8[r] = wsum(Pp * Kreg[r] * h0);
      float acc2 = 0.0f;
#pragma unroll
      for (int r1i = 0; r1i < 8; ++r1i) {
        float4 ma = *(const float4*)&M8_s[r1i*8];
        float4 mb = *(const float4*)&M8_s[r1i*8+4];
        float y = ma.x*t8[0]+ma.y*t8[1]+ma.z*t8[2]+ma.w*t8[3]
                + mb.x*t8[4]+mb.y*t8[5]+mb.z*t8[6]+mb.w*t8[7];
        acc2 = fmaf(Kreg[r1i], y, acc2);
      }
      float m0f = Pp*h0 - Pp*acc2;
      mf_s[lam] = m0f;
      outp[(size_t)b*L_ + lam] = m0f;
    }
    __syncthreads();

    const float qs0 = sqrtf(q0_r);
#pragma unroll
    for (int i = 0; i < 4; ++i) {
      const int s = 4*w + i;
      float zp = qs0 * wp2b[0][s*64 + lam];
      float v1[8];
#pragma unroll
      for (int r = 0; r < 8; ++r)
        v1[r] = wsum(Kreg[r] * zp) + wf_s[s*8 + r];
      float acc = 0.0f;
#pragma unroll
      for (int r1i = 0; r1i < 8; ++r1i) {
        float4 ma = *(const float4*)&M8_s[r1i*8];
        float4 mb = *(const float4*)&M8_s[r1i*8+4];
        float y = ma.x*v1[0]+ma.y*v1[1]+ma.z*v1[2]+ma.w*v1[3]
                + mb.x*v1[4]+mb.y*v1[5]+mb.z*v1[6]+mb.w*v1[7];
        acc = fmaf(Kreg[r1i], y, acc);
      }
      z_s[s*68 + lam] = zp - Pp*acc;   // z' excludes m_f (added in next dyn)
    }
  }
  __syncthreads();

  // ================= steps 1..T-1 =================
  for (int t = 1; t < T_; ++t) {
    const int cb = t & 1, nb = cb ^ 1;

    // per-lane K/k reload (global; hidden under P1, used from P2 on)
    {
      const float* kb = Kp + ((size_t)t*B_ + b)*(L_*R_) + lam*R_;
      float4 ka = *(const float4*)kb, kb4 = *(const float4*)(kb+4);
      Kreg[0]=ka.x;Kreg[1]=ka.y;Kreg[2]=ka.z;Kreg[3]=ka.w;
      Kreg[4]=kb4.x;Kreg[5]=kb4.y;Kreg[6]=kb4.z;Kreg[7]=kb4.w;
      kt_r = kp[((size_t)t*B_ + b)*L_ + lam];
    }

    // ---- P1 (MFMA): X = (z'+mf) @ A^T ; zn = (z'+mf) + 0.1*tanh(X) ----
    {
      f32x4 acc = {0.0f, 0.0f, 0.0f, 0.0f};
#pragma unroll
      for (int kk = 0; kk < 2; ++kk) {
        const int l0 = kk*32 + gg*8;
        const int row = mtl*16 + cc;
        float4 za = *(const float4*)&z_s[row*68 + l0];
        float4 zb = *(const float4*)&z_s[row*68 + l0 + 4];
        float4 ma4 = *(const float4*)&mf_s[l0];
        float4 mb4 = *(const float4*)&mf_s[l0 + 4];
        float z8[8] = {za.x+ma4.x, za.y+ma4.y, za.z+ma4.z, za.w+ma4.w,
                       zb.x+mb4.x, zb.y+mb4.y, zb.z+mb4.z, zb.w+mb4.w};
        short8 ah, al;
#pragma unroll
        for (int j = 0; j < 8; ++j) {
          __hip_bfloat16 hb = __float2bfloat16(z8[j]);
          ah[j] = __builtin_bit_cast(short, hb);
          float hf = __bfloat162float(hb);
          __hip_bfloat16 lb = __float2bfloat16(z8[j] - hf);
          al[j] = __builtin_bit_cast(short, lb);
        }
        acc = __builtin_amdgcn_mfma_f32_16x16x32_bf16(ah, Bh[kk], acc, 0, 0, 0);
        acc = __builtin_amdgcn_mfma_f32_16x16x32_bf16(al, Bh[kk], acc, 0, 0, 0);
        acc = __builtin_amdgcn_mfma_f32_16x16x32_bf16(ah, Bl[kk], acc, 0, 0, 0);
      }
      const int lout = ntl*16 + cc;
      const float mfl = mf_s[lout];
      float psum = 0.0f;
#pragma unroll
      for (int r = 0; r < 4; ++r) {
        const int sr = mtl*16 + gg*4 + r;
        float x = acc[r];
        float e = __expf(2.0f*x);
        float tnh = 1.0f - 2.0f/(e + 1.0f);
        float zv = (z_s[sr*68 + lout] + mfl) + 0.1f*tnh;
        zn_s[sr*68 + lout] = zv;
        psum += zv;
      }
      uni[(mtl*4 + gg)*68 + lout] = psum;   // mp partial (rows 0-7 cover all s)
    }
    bar_lgkm();  // B1

    // ---- P0: async prefetch; drains at B2 (syncthreads) ----
    if (w == 0) {
      if (t < T_-1) {
#pragma unroll
        for (int m = 0; m < 4; ++m) {
          int f = m*256 + lam*4, s = f >> 5, c = f & 31;
          gload16(wp1p + (((size_t)t*S_ + s)*B_ + b)*S_ + c, &wp1b[nb][f]);
        }
      }
    } else if (w == 1 || w == 2) {
      if (t < T_-1) {
#pragma unroll
        for (int m = 0; m < 4; ++m) {
          int f = (w-1)*1024 + m*256 + lam*4, s = f >> 6, c = f & 63;
          gload16(wp2p + (((size_t)t*S_ + s)*B_ + b)*L_ + c, &wp2b[nb][f]);
        }
      }
    } else if (w == 3) {
      { int f = lam*4, s = f >> 3, c = f & 7;
        gload16(wfp + (((size_t)(t-1)*S_ + s)*B_ + b)*R_ + c, &wf_s[f]); }
#pragma unroll
      for (int m = 0; m < 2; ++m) {
        int f = m*256 + lam*4;
        gload16(Kp + ((size_t)t*B_ + b)*(L_*R_) + f, &Kt_s[f]);
      }
    }

    // ---- P2: m_p, M_c, KM = Mc^T K, tk = Mc^T k_t (DPP) ----
    float mp = 0.0f;
#pragma unroll
    for (int ww = 0; ww < 8; ++ww) mp += uni[ww*68 + lam];
    mp *= 0.03125f;
#pragma unroll
    for (int i = 0; i < 4; ++i) {
      const int s = 4*w + i;
      float mcv = (zn_s[s*68 + lam] - mp) * 0.17677669529663689f;
      Mc_s[lam*36 + s] = mcv;
      float tkv = wredsum(mcv * kt_r);
      float kmv[8];
#pragma unroll
      for (int r = 0; r < 8; ++r) kmv[r] = wredsum(mcv * Kreg[r]);
      if (lam == 63) {
        tk_s[s] = tkv;
        *(float4*)&KM_s[s*8]   = make_float4(kmv[0],kmv[1],kmv[2],kmv[3]);
        *(float4*)&KM_s[s*8+4] = make_float4(kmv[4],kmv[5],kmv[6],kmv[7]);
      }
    }
    __syncthreads();  // B2 (full: drains prefetch vmcnt)

    // ---- P3: zprows + wave0 {u, t8 -> LDS} + wave1 {C8, M8}; then mkm ----
    float zloc[4];
    float u_r = 0.0f;
#pragma unroll
    for (int i = 0; i < 4; ++i) {
      const int s = 4*w + i;
      float acc = 0.0f;
#pragma unroll
      for (int p4 = 0; p4 < 32; p4 += 4) {
        float4 mc4 = *(const float4*)&Mc_s[lam*36 + p4];
        float4 wb  = *(const float4*)&wp1b[cb][s*32 + p4];
        acc = fmaf(mc4.x, wb.x, acc);
        acc = fmaf(mc4.y, wb.y, acc);
        acc = fmaf(mc4.z, wb.z, acc);
        acc = fmaf(mc4.w, wb.w, acc);
      }
      float zp = acc + qs_r * wp2b[cb][s*64 + lam];
      zloc[i] = zp;
      float vv[8];
#pragma unroll
      for (int r = 0; r < 8; ++r) vv[r] = wredsum(Kreg[r] * zp);
      if (lam == 63) {
        float4 wfa = *(const float4*)&wf_s[s*8];
        float4 wfb = *(const float4*)&wf_s[s*8+4];
        *(float4*)&v1t_s[s*8]   = make_float4(vv[0]+wfa.x, vv[1]+wfa.y,
                                              vv[2]+wfa.z, vv[3]+wfa.w);
        *(float4*)&v1t_s[s*8+4] = make_float4(vv[4]+wfb.x, vv[5]+wfb.y,
                                              vv[6]+wfb.z, vv[7]+wfb.w);
      }
    }
    if (w == 0) {
      // u = m_p + Mc tk + q k_t (Woodbury); t8 = K^T u -> LDS
      float mctk = 0.0f;
#pragma unroll
      for (int s4 = 0; s4 < 32; s4 += 4) {
        float4 mc4 = *(const float4*)&Mc_s[lam*36 + s4];
        float4 tb  = *(const float4*)&tk_s[s4];
        mctk = fmaf(mc4.x, tb.x, mctk);
        mctk = fmaf(mc4.y, tb.y, mctk);
        mctk = fmaf(mc4.z, tb.z, mctk);
        mctk = fmaf(mc4.w, tb.w, mctk);
      }
      u_r = mp + mctk + q_r * kt_r;
      float vv[8];
#pragma unroll
      for (int r = 0; r < 8; ++r) vv[r] = wredsum(Kreg[r] * u_r);
      if (lam == 63) {
        *(float4*)&t8_s[0] = make_float4(vv[0],vv[1],vv[2],vv[3]);
        *(float4*)&t8_s[4] = make_float4(vv[4],vv[5],vv[6],vv[7]);
      }
    } else if (w == 1) {
      const int r1 = lam >> 3, r2 = lam & 7;
      float acc = 0.0f;
#pragma unroll 4
      for (int s = 0; s < 32; ++s)
        acc = fmaf(KM_s[s*8 + r1], KM_s[s*8 + r2], acc);
#pragma unroll 4
      for (int l = 0; l < 64; ++l)
        acc = fmaf(Kt_s[l*8 + r1] * qv_s[l], Kt_s[l*8 + r2], acc);
      C8_s[lam] = acc + (r1 == r2 ? 1.0f : 0.0f);
      chol8M8();
    }
    // mkm[r] = sum_s2 Mc[lam][s2]*KM[s2][r] (Mc row b128, KM broadcast b128)
    float mkm[8];
#pragma unroll
    for (int r = 0; r < 8; ++r) mkm[r] = 0.0f;
#pragma unroll
    for (int s4 = 0; s4 < 32; s4 += 4) {
      float4 mc4 = *(const float4*)&Mc_s[lam*36 + s4];
#pragma unroll
      for (int ii = 0; ii < 4; ++ii) {
        const float mcl = (ii==0)?mc4.x:(ii==1)?mc4.y:(ii==2)?mc4.z:mc4.w;
        float4 ka = *(const float4*)&KM_s[(s4+ii)*8];
        float4 kb = *(const float4*)&KM_s[(s4+ii)*8+4];
        mkm[0] = fmaf(mcl, ka.x, mkm[0]);
        mkm[1] = fmaf(mcl, ka.y, mkm[1]);
        mkm[2] = fmaf(mcl, ka.z, mkm[2]);
        mkm[3] = fmaf(mcl, ka.w, mkm[3]);
        mkm[4] = fmaf(mcl, kb.x, mkm[4]);
        mkm[5] = fmaf(mcl, kb.y, mkm[5]);
        mkm[6] = fmaf(mcl, kb.z, mkm[6]);
        mkm[7] = fmaf(mcl, kb.w, mkm[7]);
      }
    }
    bar_lgkm();  // B3 (M8_s, v1t_s, t8_s visible)

    // ---- P4: fold M8 once per lane (symmetric): kM8 = M8 K, mkmM8 = M8 mkm ----
    float kM8[8], mkmM8[8];
#pragma unroll
    for (int j = 0; j < 8; ++j) { kM8[j] = 0.0f; mkmM8[j] = 0.0f; }
#pragma unroll
    for (int r = 0; r < 8; ++r) {
      float4 ma = *(const float4*)&M8_s[r*8];
      float4 mb = *(const float4*)&M8_s[r*8+4];
      const float kr = Kreg[r], mr = mkm[r];
      kM8[0] = fmaf(kr, ma.x, kM8[0]);   mkmM8[0] = fmaf(mr, ma.x, mkmM8[0]);
      kM8[1] = fmaf(kr, ma.y, kM8[1]);   mkmM8[1] = fmaf(mr, ma.y, mkmM8[1]);
      kM8[2] = fmaf(kr, ma.z, kM8[2]);   mkmM8[2] = fmaf(mr, ma.z, mkmM8[2]);
      kM8[3] = fmaf(kr, ma.w, kM8[3]);   mkmM8[3] = fmaf(mr, ma.w, mkmM8[3]);
      kM8[4] = fmaf(kr, mb.x, kM8[4]);   mkmM8[4] = fmaf(mr, mb.x, mkmM8[4]);
      kM8[5] = fmaf(kr, mb.y, kM8[5]);   mkmM8[5] = fmaf(mr, mb.y, mkmM8[5]);
      kM8[6] = fmaf(kr, mb.z, kM8[6]);   mkmM8[6] = fmaf(mr, mb.z, mkmM8[6]);
      kM8[7] = fmaf(kr, mb.w, kM8[7]);   mkmM8[7] = fmaf(mr, mb.w, mkmM8[7]);
    }
    // per row: g = kM8 . v1t, corr = mkmM8 . v1t  (2 b128 + 16 FMA)
#pragma unroll
    for (int i = 0; i < 4; ++i) {
      const int s = 4*w + i;
      float4 va = *(const float4*)&v1t_s[s*8];
      float4 vb = *(const float4*)&v1t_s[s*8+4];
      float g    = kM8[0]*va.x + kM8[1]*va.y + kM8[2]*va.z + kM8[3]*va.w
                 + kM8[4]*vb.x + kM8[5]*vb.y + kM8[6]*vb.z + kM8[7]*vb.w;
      float corr = mkmM8[0]*va.x + mkmM8[1]*va.y + mkmM8[2]*va.z + mkmM8[3]*va.w
                 + mkmM8[4]*vb.x + mkmM8[5]*vb.y + mkmM8[6]*vb.z + mkmM8[7]*vb.w;
      z_s[s*68 + lam] = zloc[i] - corr - q_r*g;   // z' (mf added next dyn)
    }
    if (w == 0) {   // mf tail: t8 from LDS; mf = u - mkmM8.t8 - q*(kM8.t8)
      float4 ta = *(const float4*)&t8_s[0];
      float4 tb = *(const float4*)&t8_s[4];
      float g    = kM8[0]*ta.x + kM8[1]*ta.y + kM8[2]*ta.z + kM8[3]*ta.w
                 + kM8[4]*tb.x + kM8[5]*tb.y + kM8[6]*tb.z + kM8[7]*tb.w;
      float corr = mkmM8[0]*ta.x + mkmM8[1]*ta.y + mkmM8[2]*ta.z + mkmM8[3]*ta.w
                 + mkmM8[4]*tb.x + mkmM8[5]*tb.y + mkmM8[6]*tb.z + mkmM8[7]*tb.w;
      const float mf_r = u_r - corr - q_r*g;
      mf_s[lam] = mf_r;
      outp[((size_t)t*B_ + b)*L_ + lam] = mf_r;
    }
    bar_lgkm();  // B4 (mf_s, z_s visible for next P1)
  }
}

extern "C" void kernel_launch(void* const* d_in, const int* in_sizes, int n_in,
                              void* d_out, int out_size, void* d_ws, size_t ws_size,
                              hipStream_t stream) {
  (void)in_sizes; (void)n_in; (void)out_size; (void)d_ws; (void)ws_size;
  nlf_kernel<<<dim3(B_), dim3(512), 0, stream>>>(
      (const float*)d_in[0], (const float*)d_in[1], (const float*)d_in[2],
      (const float*)d_in[3], (const float*)d_in[4], (const float*)d_in[5],
      (const float*)d_in[6], (const float*)d_in[7], (const float*)d_in[8],
      (const float*)d_in[9], (const float*)d_in[10], (float*)d_out);
}

// Round 14
// 2703.817 us; speedup vs baseline: 2.2958x; 1.7512x over previous
//
#include <hip/hip_runtime.h>
#include <hip/hip_bf16.h>
#include <cstdint>
#include <cstddef>

namespace {
constexpr int T_ = 500, S_ = 32, B_ = 128, L_ = 64, R_ = 8;

typedef __attribute__((ext_vector_type(8))) short short8;
typedef __attribute__((ext_vector_type(4))) float f32x4;

__device__ __forceinline__ float rdlane(float v, int l) {
  return __int_as_float(__builtin_amdgcn_readlane(__float_as_int(v), l));
}
template<int CTRL, int RM>
__device__ __forceinline__ float dppadd(float v) {
  int t = __builtin_amdgcn_update_dpp(0, __float_as_int(v), CTRL, RM, 0xf, false);
  return v + __int_as_float(t);
}
// full 64-lane sum; total lands in lane 63 (VALU-only, no DS)
__device__ __forceinline__ float wredsum(float v) {
  v = dppadd<0x111, 0xf>(v);   // row_shr:1
  v = dppadd<0x112, 0xf>(v);   // row_shr:2
  v = dppadd<0x114, 0xf>(v);   // row_shr:4
  v = dppadd<0x118, 0xf>(v);   // row_shr:8
  v = dppadd<0x142, 0xa>(v);   // row_bcast:15 -> rows 1,3
  v = dppadd<0x143, 0xc>(v);   // row_bcast:31 -> rows 2,3
  return v;
}
__device__ __forceinline__ float wsum(float v) {  // all-lanes result (step0 only)
  v += __shfl_xor(v, 1);  v += __shfl_xor(v, 2);  v += __shfl_xor(v, 4);
  v += __shfl_xor(v, 8);  v += __shfl_xor(v, 16); v += __shfl_xor(v, 32);
  return v;
}
__device__ __forceinline__ void gload16(const float* g, float* l) {
  __builtin_amdgcn_global_load_lds((const __attribute__((address_space(1))) uint32_t*)g,
                                   (__attribute__((address_space(3))) uint32_t*)l,
                                   16, 0, 0);
}
// barrier that drains LDS ops but lets global loads/stores ride (vmcnt untouched)
__device__ __forceinline__ void bar_lgkm() {
  asm volatile("s_waitcnt lgkmcnt(0)\n\ts_barrier" ::: "memory");
}
__device__ __forceinline__ void splitbf16(const float (&v)[8], short8& hi, short8& lo) {
#pragma unroll
  for (int j = 0; j < 8; ++j) {
    __hip_bfloat16 hb = __float2bfloat16(v[j]);
    hi[j] = __builtin_bit_cast(short, hb);
    float hf = __bfloat162float(hb);
    __hip_bfloat16 lb = __float2bfloat16(v[j] - hf);
    lo[j] = __builtin_bit_cast(short, lb);
  }
}
__device__ __forceinline__ void ldfrag(const float* p, short8& hi, short8& lo) {
  float4 a = *(const float4*)p, b = *(const float4*)(p + 4);
  float v[8] = {a.x,a.y,a.z,a.w,b.x,b.y,b.z,b.w};
  splitbf16(v, hi, lo);
}
__device__ __forceinline__ f32x4 mfma3(short8 ah, short8 al, short8 bh, short8 bl,
                                       f32x4 acc) {
  acc = __builtin_amdgcn_mfma_f32_16x16x32_bf16(ah, bh, acc, 0, 0, 0);
  acc = __builtin_amdgcn_mfma_f32_16x16x32_bf16(al, bh, acc, 0, 0, 0);
  acc = __builtin_amdgcn_mfma_f32_16x16x32_bf16(ah, bl, acc, 0, 0, 0);
  return acc;
}
}  // namespace

// One block per batch element b. 512 threads = 8 waves, 4 ensemble rows/wave.
// All big per-step products on the matrix pipe (split-bf16 ~ fp32):
//  P1:  zn-pre  X  = (z'+mf) @ A^T          (R13, verified)
//  P3a: z_p     zp = wp1 @ Mc^T (+ qs*wp2)  8 tiles, waves 2-7
//       KM|tk   [Mc^T K | Mc^T k_t]          2 tiles, waves 0-1
//  P3b: v1t     zp @ K (+ wf)                2 tiles, waves 2-3
//       C8+chol8 (w1, KtT b128), u+t8 (w0), mkm once (w4 -> mkm_s)
//  P4:  per-row M8-folded corrections (no cross-lane), mf tail (w0)
__global__ __launch_bounds__(512, 1) void nlf_kernel(
    const float* __restrict__ m0p, const float* __restrict__ q0p,
    const float* __restrict__ qp,  const float* __restrict__ kp,
    const float* __restrict__ Kp,  const float* __restrict__ Ap,
    const float* __restrict__ wp0p, const float* __restrict__ wf0p,
    const float* __restrict__ wp1p, const float* __restrict__ wp2p,
    const float* __restrict__ wfp,  float* __restrict__ outp)
{
  __shared__ __align__(16) float z_s[S_*68];      // carry z' (z - mf)
  __shared__ __align__(16) float zn_s[S_*68];     // zn (P1->P2), then zp (P3a->P4)
  __shared__ __align__(16) float Mc_s[L_*36];     // M_c by l-rows
  __shared__ __align__(16) float McT_s[S_*68];    // M_c by s-rows
  __shared__ __align__(16) float uni[8*68];       // mp partials
  __shared__ __align__(16) float wp1b[2][S_*S_];
  __shared__ __align__(16) float wp2b[2][S_*L_];
  __shared__ __align__(16) float wf_s[S_*R_];
  __shared__ __align__(16) float Ktb[2][L_*R_];   // K double-buffer (by l-rows)
  __shared__ __align__(16) float KtT_s[R_*68];    // K^T (by r-rows)
  __shared__ __align__(16) float ktv_s[L_];       // k_t vector
  __shared__ __align__(16) float v1t_s[S_*R_];
  __shared__ __align__(16) float KM_s[S_*R_];     // (Mc^T K)[s][r]
  __shared__ __align__(16) float mkm_s[L_*R_];    // per-lam mkm (w4 -> all)
  __shared__ __align__(16) float M8_s[64];
  __shared__ __align__(16) float C8_s[64];
  __shared__ __align__(16) float tk_s[S_];        // Mc^T k_t
  __shared__ __align__(16) float mf_s[L_];
  __shared__ __align__(16) float qv_s[L_];
  __shared__ __align__(16) float qsv_s[L_];
  __shared__ __align__(16) float q0v_s[L_];

  const int tid = threadIdx.x;
  const int lam = tid & 63;
  const int w   = tid >> 6;
  const int b   = blockIdx.x;
  const int mtl = w >> 2, ntl = w & 3;      // MFMA tile coords (P1)
  const int cc  = lam & 15, gg = lam >> 4;  // MFMA lane coords

  const float q_r  = qp[lam];
  const float qs_r = sqrtf(q_r);
  const float q0_r = q0p[lam];
  const float m0_r = m0p[lam];
  if (tid < 64) { qv_s[tid] = q_r; qsv_s[tid] = qs_r; q0v_s[tid] = q0_r; }

  // ---- A^T fragments (static): B-op lane holds A[ntl*16+cc][kk*32+gg*8+j] ----
  short8 ABh[2], ABl[2];
  {
    const float* arow = Ap + (size_t)(ntl*16 + cc)*64;
#pragma unroll
    for (int kk = 0; kk < 2; ++kk) {
      float v[8];
      float4 a4 = *(const float4*)(arow + kk*32 + gg*8);
      float4 b4 = *(const float4*)(arow + kk*32 + gg*8 + 4);
      v[0]=a4.x;v[1]=a4.y;v[2]=a4.z;v[3]=a4.w;v[4]=b4.x;v[5]=b4.y;v[6]=b4.z;v[7]=b4.w;
      splitbf16(v, ABh[kk], ABl[kk]);
    }
  }

  float Kreg[8];
  {
    const float* kb = Kp + (size_t)b*(L_*R_) + lam*R_;
    float4 ka = *(const float4*)kb, kb4 = *(const float4*)(kb+4);
    Kreg[0]=ka.x;Kreg[1]=ka.y;Kreg[2]=ka.z;Kreg[3]=ka.w;
    Kreg[4]=kb4.x;Kreg[5]=kb4.y;Kreg[6]=kb4.z;Kreg[7]=kb4.w;
  }
  float kt_r = kp[(size_t)b*L_ + lam];

  // ---- prologue async loads ----
  if (w == 0) {                       // wp1[0] -> wp1b[1]
#pragma unroll
    for (int m = 0; m < 4; ++m) {
      int f = m*256 + lam*4, s = f >> 5, c = f & 31;
      gload16(wp1p + ((size_t)s*B_ + b)*S_ + c, &wp1b[1][f]);
    }
  } else if (w == 1 || w == 2) {      // wp2[0] -> wp2b[1]
#pragma unroll
    for (int m = 0; m < 4; ++m) {
      int f = (w-1)*1024 + m*256 + lam*4, s = f >> 6, c = f & 63;
      gload16(wp2p + ((size_t)s*B_ + b)*L_ + c, &wp2b[1][f]);
    }
  } else if (w == 3) {                // wf0 -> wf_s ; K[0] -> Ktb[0]
    { int f = lam*4, s = f >> 3, c = f & 7;
      gload16(wf0p + ((size_t)s*B_ + b)*R_ + c, &wf_s[f]); }
#pragma unroll
    for (int m = 0; m < 2; ++m) {
      int f = m*256 + lam*4;
      gload16(Kp + (size_t)b*(L_*R_) + f, &Ktb[0][f]);
    }
  } else if (w == 4 || w == 5) {      // w_p0 -> wp2b[0]
#pragma unroll
    for (int m = 0; m < 4; ++m) {
      int f = (w-4)*1024 + m*256 + lam*4, s = f >> 6, c = f & 63;
      gload16(wp0p + ((size_t)s*B_ + b)*L_ + c, &wp2b[0][f]);
    }
  } else if (w == 6) {                // K[1] -> Ktb[1]
#pragma unroll
    for (int m = 0; m < 2; ++m) {
      int f = m*256 + lam*4;
      gload16(Kp + ((size_t)1*B_ + b)*(L_*R_) + f, &Ktb[1][f]);
    }
  }
  __syncthreads();

  // 8x8 SPD: C8_s -> M8_s = inv(C8) via in-register Cholesky (rows in lanes 0-7)
  auto chol8M8 = [&]() {
    const int i8 = lam & 7;
    float c8[8], rd8 = 0.0f;
#pragma unroll
    for (int k = 0; k < 8; ++k) c8[k] = C8_s[i8*8 + k];
#pragma unroll
    for (int j = 0; j < 8; ++j) {
      float dj = rdlane(c8[j], j);
      float rinv = rsqrtf(dj);
      if (i8 == j) rd8 = rinv;
      c8[j] *= rinv;
#pragma unroll
      for (int k = j+1; k < 8; ++k)
        c8[k] = fmaf(-rdlane(c8[j], k), c8[j], c8[k]);
    }
    float w8[8];
#pragma unroll
    for (int i = 0; i < 8; ++i) {
      float sacc = (i == i8) ? 1.0f : 0.0f;
#pragma unroll
      for (int k = 0; k < i; ++k)
        sacc = fmaf(-rdlane(c8[k], i), w8[k], sacc);
      w8[i] = sacc * rdlane(rd8, i);
    }
#pragma unroll
    for (int i = 0; i < 8; ++i) {
      float msum = 0.0f;
#pragma unroll
      for (int k = 0; k < 8; ++k)
        msum = fmaf(rdlane(w8[k], i), w8[k], msum);
      if (lam < 8) M8_s[i*8 + lam] = msum;
    }
  };

  // ================= step 0 =================
  {
    const float Pp = q0_r;
    const float h0 = m0_r / Pp + kt_r;
    if (w == 0) {
      const int r1 = lam >> 3, r2 = lam & 7;
      float acc = 0.0f;
#pragma unroll 4
      for (int l = 0; l < 64; ++l)
        acc = fmaf(Ktb[0][l*8 + r1] * q0v_s[l], Ktb[0][l*8 + r2], acc);
      C8_s[lam] = acc + (r1 == r2 ? 1.0f : 0.0f);
      chol8M8();
      float t8[8];
#pragma unroll
      for (int r = 0; r < 8; ++r) t8[r] = wsum(Pp * Kreg[r] * h0);
      float acc2 = 0.0f;
#pragma unroll
      for (int r1i = 0; r1i < 8; ++r1i) {
        float4 ma = *(const float4*)&M8_s[r1i*8];
        float4 mb = *(const float4*)&M8_s[r1i*8+4];
        float y = ma.x*t8[0]+ma.y*t8[1]+ma.z*t8[2]+ma.w*t8[3]
                + mb.x*t8[4]+mb.y*t8[5]+mb.z*t8[6]+mb.w*t8[7];
        acc2 = fmaf(Kreg[r1i], y, acc2);
      }
      float m0f = Pp*h0 - Pp*acc2;
      mf_s[lam] = m0f;
      outp[(size_t)b*L_ + lam] = m0f;
    }
    __syncthreads();

    const float qs0 = sqrtf(q0_r);
#pragma unroll
    for (int i = 0; i < 4; ++i) {
      const int s = 4*w + i;
      float zp = qs0 * wp2b[0][s*64 + lam];
      float v1[8];
#pragma unroll
      for (int r = 0; r < 8; ++r)
        v1[r] = wsum(Kreg[r] * zp) + wf_s[s*8 + r];
      float acc = 0.0f;
#pragma unroll
      for (int r1i = 0; r1i < 8; ++r1i) {
        float4 ma = *(const float4*)&M8_s[r1i*8];
        float4 mb = *(const float4*)&M8_s[r1i*8+4];
        float y = ma.x*v1[0]+ma.y*v1[1]+ma.z*v1[2]+ma.w*v1[3]
                + mb.x*v1[4]+mb.y*v1[5]+mb.z*v1[6]+mb.w*v1[7];
        acc = fmaf(Kreg[r1i], y, acc);
      }
      z_s[s*68 + lam] = zp - Pp*acc;   // z' excludes m_f (added in next dyn)
    }
  }
  __syncthreads();

  // ================= steps 1..T-1 =================
  for (int t = 1; t < T_; ++t) {
    const int cb = t & 1, nb = cb ^ 1;

    // per-lane K/k reload (global; used P4 + t8)
    {
      const float* kb = Kp + ((size_t)t*B_ + b)*(L_*R_) + lam*R_;
      float4 ka = *(const float4*)kb, kb4 = *(const float4*)(kb+4);
      Kreg[0]=ka.x;Kreg[1]=ka.y;Kreg[2]=ka.z;Kreg[3]=ka.w;
      Kreg[4]=kb4.x;Kreg[5]=kb4.y;Kreg[6]=kb4.z;Kreg[7]=kb4.w;
      kt_r = kp[((size_t)t*B_ + b)*L_ + lam];
    }
    if (w == 0) ktv_s[lam] = kt_r;

    // ---- P1 (MFMA): X = (z'+mf) @ A^T ; zn = (z'+mf) + 0.1*tanh(X) ----
    {
      f32x4 acc = {0.0f, 0.0f, 0.0f, 0.0f};
#pragma unroll
      for (int kk = 0; kk < 2; ++kk) {
        const int l0 = kk*32 + gg*8;
        const int row = mtl*16 + cc;
        float4 za = *(const float4*)&z_s[row*68 + l0];
        float4 zb = *(const float4*)&z_s[row*68 + l0 + 4];
        float4 ma4 = *(const float4*)&mf_s[l0];
        float4 mb4 = *(const float4*)&mf_s[l0 + 4];
        float z8[8] = {za.x+ma4.x, za.y+ma4.y, za.z+ma4.z, za.w+ma4.w,
                       zb.x+mb4.x, zb.y+mb4.y, zb.z+mb4.z, zb.w+mb4.w};
        short8 ah, al;
        splitbf16(z8, ah, al);
        acc = __builtin_amdgcn_mfma_f32_16x16x32_bf16(ah, ABh[kk], acc, 0, 0, 0);
        acc = __builtin_amdgcn_mfma_f32_16x16x32_bf16(al, ABh[kk], acc, 0, 0, 0);
        acc = __builtin_amdgcn_mfma_f32_16x16x32_bf16(ah, ABl[kk], acc, 0, 0, 0);
      }
      const int lout = ntl*16 + cc;
      const float mfl = mf_s[lout];
      float psum = 0.0f;
#pragma unroll
      for (int r = 0; r < 4; ++r) {
        const int sr = mtl*16 + gg*4 + r;
        float x = acc[r];
        float e = __expf(2.0f*x);
        float tnh = 1.0f - 2.0f/(e + 1.0f);
        float zv = (z_s[sr*68 + lout] + mfl) + 0.1f*tnh;
        zn_s[sr*68 + lout] = zv;
        psum += zv;
      }
      uni[(mtl*4 + gg)*68 + lout] = psum;
    }
    bar_lgkm();  // B1

    // ---- P0: async prefetch; drains at B2 (syncthreads) ----
    if (w == 0) {
      if (t < T_-1) {
#pragma unroll
        for (int m = 0; m < 4; ++m) {
          int f = m*256 + lam*4, s = f >> 5, c = f & 31;
          gload16(wp1p + (((size_t)t*S_ + s)*B_ + b)*S_ + c, &wp1b[nb][f]);
        }
      }
    } else if (w == 1 || w == 2) {
      if (t < T_-1) {
#pragma unroll
        for (int m = 0; m < 4; ++m) {
          int f = (w-1)*1024 + m*256 + lam*4, s = f >> 6, c = f & 63;
          gload16(wp2p + (((size_t)t*S_ + s)*B_ + b)*L_ + c, &wp2b[nb][f]);
        }
      }
    } else if (w == 3) {
      { int f = lam*4, s = f >> 3, c = f & 7;
        gload16(wfp + (((size_t)(t-1)*S_ + s)*B_ + b)*R_ + c, &wf_s[f]); }
      if (t < T_-1) {
#pragma unroll
        for (int m = 0; m < 2; ++m) {
          int f = m*256 + lam*4;
          gload16(Kp + ((size_t)(t+1)*B_ + b)*(L_*R_) + f, &Ktb[nb][f]);
        }
      }
    }

    // ---- P2: m_p, Mc (both layouts), KtT transpose (w5) ----
    float mp = 0.0f;
#pragma unroll
    for (int ww = 0; ww < 8; ++ww) mp += uni[ww*68 + lam];
    mp *= 0.03125f;
#pragma unroll
    for (int i = 0; i < 4; ++i) {
      const int s = 4*w + i;
      float mcv = (zn_s[s*68 + lam] - mp) * 0.17677669529663689f;
      Mc_s[lam*36 + s] = mcv;
      McT_s[s*68 + lam] = mcv;
    }
    if (w == 5) {   // KtT[r][l] = Ktb[cb][l][r]
      float4 a = *(const float4*)&Ktb[cb][lam*8];
      float4 c4 = *(const float4*)&Ktb[cb][lam*8+4];
      KtT_s[0*68+lam]=a.x;  KtT_s[1*68+lam]=a.y;
      KtT_s[2*68+lam]=a.z;  KtT_s[3*68+lam]=a.w;
      KtT_s[4*68+lam]=c4.x; KtT_s[5*68+lam]=c4.y;
      KtT_s[6*68+lam]=c4.z; KtT_s[7*68+lam]=c4.w;
    }
    __syncthreads();  // B2 (full: drains prefetch vmcnt)

    // ---- P3a: zp tiles (w2-7) + KM|tk tiles (w0-1) ----
    if (w >= 2) {
      // zp[s][l] = sum_s2 wp1[s][s2]*Mc[l][s2]  (+ qs*wp2)
      auto zpTile = [&](int tl) {
        const int mt = tl >> 2, nt = tl & 3;
        short8 ah, al, bh, bl;
        ldfrag(&wp1b[cb][(mt*16+cc)*32 + gg*8], ah, al);
        ldfrag(&Mc_s[(nt*16+cc)*36 + gg*8], bh, bl);
        f32x4 acc = {0,0,0,0};
        acc = mfma3(ah, al, bh, bl, acc);
        const int col = nt*16 + cc;
        const float qsc = qsv_s[col];
#pragma unroll
        for (int r = 0; r < 4; ++r) {
          const int row = mt*16 + gg*4 + r;
          zn_s[row*68 + col] = acc[r] + qsc * wp2b[cb][row*64 + col];
        }
      };
      if (w <= 5) zpTile(w - 2);
      else { zpTile(2*w - 8); zpTile(2*w - 7); }   // w6:{4,5} w7:{6,7}
    } else {
      // [KM | tk][s][c] = sum_l Mc[l][s] * [K[l][c] | kt[l]]
      const int mt = w;
      f32x4 acc = {0,0,0,0};
#pragma unroll
      for (int ks = 0; ks < 2; ++ks) {
        short8 ah, al, bh, bl;
        ldfrag(&McT_s[(mt*16+cc)*68 + ks*32 + gg*8], ah, al);
        float bv[8] = {0,0,0,0,0,0,0,0};
        if (cc < 8) {
          float4 x = *(const float4*)&KtT_s[cc*68 + ks*32 + gg*8];
          float4 y = *(const float4*)&KtT_s[cc*68 + ks*32 + gg*8 + 4];
          bv[0]=x.x;bv[1]=x.y;bv[2]=x.z;bv[3]=x.w;
          bv[4]=y.x;bv[5]=y.y;bv[6]=y.z;bv[7]=y.w;
        } else if (cc == 8) {
#pragma unroll
          for (int j = 0; j < 8; ++j) bv[j] = ktv_s[ks*32 + gg*8 + j];
        }
        splitbf16(bv, bh, bl);
        acc = mfma3(ah, al, bh, bl, acc);
      }
#pragma unroll
      for (int r = 0; r < 4; ++r) {
        const int s = mt*16 + gg*4 + r;
        if (cc < 8) KM_s[s*8 + cc] = acc[r];
        else if (cc == 8) tk_s[s] = acc[r];
      }
    }
    bar_lgkm();  // B2b (zp, KM, tk visible)

    // ---- P3b: v1t tiles (w2-3), C8+chol8 (w1), u+t8 (w0), mkm (w4) ----
    float u_r = 0.0f, t8s[8];
#pragma unroll
    for (int r = 0; r < 8; ++r) t8s[r] = 0.0f;
    if (w == 0) {
      float mctk = 0.0f;
#pragma unroll
      for (int s4 = 0; s4 < 32; s4 += 4) {
        float4 mc4 = *(const float4*)&Mc_s[lam*36 + s4];
        float4 tb  = *(const float4*)&tk_s[s4];
        mctk = fmaf(mc4.x, tb.x, mctk);
        mctk = fmaf(mc4.y, tb.y, mctk);
        mctk = fmaf(mc4.z, tb.z, mctk);
        mctk = fmaf(mc4.w, tb.w, mctk);
      }
      u_r = mp + mctk + q_r * kt_r;
#pragma unroll
      for (int r = 0; r < 8; ++r)
        t8s[r] = rdlane(wredsum(Kreg[r] * u_r), 63);
    } else if (w == 1) {
      const int r1 = lam >> 3, r2 = lam & 7;
      float acc = 0.0f;
#pragma unroll 4
      for (int s = 0; s < 32; ++s)
        acc = fmaf(KM_s[s*8 + r1], KM_s[s*8 + r2], acc);
#pragma unroll 4
      for (int l4 = 0; l4 < 64; l4 += 4) {
        float4 ka = *(const float4*)&KtT_s[r1*68 + l4];
        float4 kb = *(const float4*)&KtT_s[r2*68 + l4];
        float4 qv4 = *(const float4*)&qv_s[l4];
        acc = fmaf(ka.x*qv4.x, kb.x, acc);
        acc = fmaf(ka.y*qv4.y, kb.y, acc);
        acc = fmaf(ka.z*qv4.z, kb.z, acc);
        acc = fmaf(ka.w*qv4.w, kb.w, acc);
      }
      C8_s[lam] = acc + (r1 == r2 ? 1.0f : 0.0f);
      chol8M8();
    } else if (w == 2 || w == 3) {
      // v1t[s][r] = sum_l zp[s][l]*K[l][r] + wf
      const int mt = w - 2;
      f32x4 acc = {0,0,0,0};
#pragma unroll
      for (int ks = 0; ks < 2; ++ks) {
        short8 ah, al, bh, bl;
        ldfrag(&zn_s[(mt*16+cc)*68 + ks*32 + gg*8], ah, al);
        float bv[8] = {0,0,0,0,0,0,0,0};
        if (cc < 8) {
          float4 x = *(const float4*)&KtT_s[cc*68 + ks*32 + gg*8];
          float4 y = *(const float4*)&KtT_s[cc*68 + ks*32 + gg*8 + 4];
          bv[0]=x.x;bv[1]=x.y;bv[2]=x.z;bv[3]=x.w;
          bv[4]=y.x;bv[5]=y.y;bv[6]=y.z;bv[7]=y.w;
        }
        splitbf16(bv, bh, bl);
        acc = mfma3(ah, al, bh, bl, acc);
      }
#pragma unroll
      for (int r = 0; r < 4; ++r) {
        const int s = mt*16 + gg*4 + r;
        if (cc < 8) v1t_s[s*8 + cc] = acc[r] + wf_s[s*8 + cc];
      }
    } else if (w == 4) {
      // mkm[r] = sum_s2 Mc[lam][s2]*KM[s2][r]  (once; published for all)
      float mkm[8];
#pragma unroll
      for (int r = 0; r < 8; ++r) mkm[r] = 0.0f;
#pragma unroll
      for (int s4 = 0; s4 < 32; s4 += 4) {
        float4 mc4 = *(const float4*)&Mc_s[lam*36 + s4];
#pragma unroll
        for (int ii = 0; ii < 4; ++ii) {
          const float mcl = (ii==0)?mc4.x:(ii==1)?mc4.y:(ii==2)?mc4.z:mc4.w;
          float4 ka = *(const float4*)&KM_s[(s4+ii)*8];
          float4 kb = *(const float4*)&KM_s[(s4+ii)*8+4];
          mkm[0] = fmaf(mcl, ka.x, mkm[0]);
          mkm[1] = fmaf(mcl, ka.y, mkm[1]);
          mkm[2] = fmaf(mcl, ka.z, mkm[2]);
          mkm[3] = fmaf(mcl, ka.w, mkm[3]);
          mkm[4] = fmaf(mcl, kb.x, mkm[4]);
          mkm[5] = fmaf(mcl, kb.y, mkm[5]);
          mkm[6] = fmaf(mcl, kb.z, mkm[6]);
          mkm[7] = fmaf(mcl, kb.w, mkm[7]);
        }
      }
      *(float4*)&mkm_s[lam*8]   = make_float4(mkm[0],mkm[1],mkm[2],mkm[3]);
      *(float4*)&mkm_s[lam*8+4] = make_float4(mkm[4],mkm[5],mkm[6],mkm[7]);
    }
    bar_lgkm();  // B3 (M8_s, v1t_s, mkm_s visible)

    // ---- P4: fold M8 once per lane (symmetric): kM8 = M8 K, mkmM8 = M8 mkm ----
    float4 mk_a = *(const float4*)&mkm_s[lam*8];
    float4 mk_b = *(const float4*)&mkm_s[lam*8+4];
    const float mkmv[8] = {mk_a.x, mk_a.y, mk_a.z, mk_a.w,
                           mk_b.x, mk_b.y, mk_b.z, mk_b.w};
    float kM8[8], mkmM8[8];
#pragma unroll
    for (int j = 0; j < 8; ++j) { kM8[j] = 0.0f; mkmM8[j] = 0.0f; }
#pragma unroll
    for (int r = 0; r < 8; ++r) {
      float4 ma = *(const float4*)&M8_s[r*8];
      float4 mb = *(const float4*)&M8_s[r*8+4];
      const float kr = Kreg[r], mr = mkmv[r];
      kM8[0] = fmaf(kr, ma.x, kM8[0]);   mkmM8[0] = fmaf(mr, ma.x, mkmM8[0]);
      kM8[1] = fmaf(kr, ma.y, kM8[1]);   mkmM8[1] = fmaf(mr, ma.y, mkmM8[1]);
      kM8[2] = fmaf(kr, ma.z, kM8[2]);   mkmM8[2] = fmaf(mr, ma.z, mkmM8[2]);
      kM8[3] = fmaf(kr, ma.w, kM8[3]);   mkmM8[3] = fmaf(mr, ma.w, mkmM8[3]);
      kM8[4] = fmaf(kr, mb.x, kM8[4]);   mkmM8[4] = fmaf(mr, mb.x, mkmM8[4]);
      kM8[5] = fmaf(kr, mb.y, kM8[5]);   mkmM8[5] = fmaf(mr, mb.y, mkmM8[5]);
      kM8[6] = fmaf(kr, mb.z, kM8[6]);   mkmM8[6] = fmaf(mr, mb.z, mkmM8[6]);
      kM8[7] = fmaf(kr, mb.w, kM8[7]);   mkmM8[7] = fmaf(mr, mb.w, mkmM8[7]);
    }
#pragma unroll
    for (int i = 0; i < 4; ++i) {
      const int s = 4*w + i;
      float4 va = *(const float4*)&v1t_s[s*8];
      float4 vb = *(const float4*)&v1t_s[s*8+4];
      float g    = kM8[0]*va.x + kM8[1]*va.y + kM8[2]*va.z + kM8[3]*va.w
                 + kM8[4]*vb.x + kM8[5]*vb.y + kM8[6]*vb.z + kM8[7]*vb.w;
      float corr = mkmM8[0]*va.x + mkmM8[1]*va.y + mkmM8[2]*va.z + mkmM8[3]*va.w
                 + mkmM8[4]*vb.x + mkmM8[5]*vb.y + mkmM8[6]*vb.z + mkmM8[7]*vb.w;
      float zp = zn_s[s*68 + lam];
      z_s[s*68 + lam] = zp - corr - q_r*g;   // z' (mf added next dyn)
    }
    if (w == 0) {   // mf tail
      float g    = kM8[0]*t8s[0] + kM8[1]*t8s[1] + kM8[2]*t8s[2] + kM8[3]*t8s[3]
                 + kM8[4]*t8s[4] + kM8[5]*t8s[5] + kM8[6]*t8s[6] + kM8[7]*t8s[7];
      float corr = mkmM8[0]*t8s[0] + mkmM8[1]*t8s[1] + mkmM8[2]*t8s[2] + mkmM8[3]*t8s[3]
                 + mkmM8[4]*t8s[4] + mkmM8[5]*t8s[5] + mkmM8[6]*t8s[6] + mkmM8[7]*t8s[7];
      const float mf_r = u_r - corr - q_r*g;
      mf_s[lam] = mf_r;
      outp[((size_t)t*B_ + b)*L_ + lam] = mf_r;
    }
    bar_lgkm();  // B4 (mf_s, z_s visible for next P1)
  }
}

extern "C" void kernel_launch(void* const* d_in, const int* in_sizes, int n_in,
                              void* d_out, int out_size, void* d_ws, size_t ws_size,
                              hipStream_t stream) {
  (void)in_sizes; (void)n_in; (void)out_size; (void)d_ws; (void)ws_size;
  nlf_kernel<<<dim3(B_), dim3(512), 0, stream>>>(
      (const float*)d_in[0], (const float*)d_in[1], (const float*)d_in[2],
      (const float*)d_in[3], (const float*)d_in[4], (const float*)d_in[5],
      (const float*)d_in[6], (const float*)d_in[7], (const float*)d_in[8],
      (const float*)d_in[9], (const float*)d_in[10], (float*)d_out);
}

// Round 15
// 2669.749 us; speedup vs baseline: 2.3251x; 1.0128x over previous
//
#include <hip/hip_runtime.h>
#include <hip/hip_bf16.h>
#include <cstdint>
#include <cstddef>

namespace {
constexpr int T_ = 500, S_ = 32, B_ = 128, L_ = 64, R_ = 8;

typedef __attribute__((ext_vector_type(8))) short short8;
typedef __attribute__((ext_vector_type(4))) float f32x4;

__device__ __forceinline__ float rdlane(float v, int l) {
  return __int_as_float(__builtin_amdgcn_readlane(__float_as_int(v), l));
}
template<int CTRL, int RM>
__device__ __forceinline__ float dppadd(float v) {
  int t = __builtin_amdgcn_update_dpp(0, __float_as_int(v), CTRL, RM, 0xf, false);
  return v + __int_as_float(t);
}
// full 64-lane sum; total lands in lane 63 (VALU-only, no DS)
__device__ __forceinline__ float wredsum(float v) {
  v = dppadd<0x111, 0xf>(v);   // row_shr:1
  v = dppadd<0x112, 0xf>(v);   // row_shr:2
  v = dppadd<0x114, 0xf>(v);   // row_shr:4
  v = dppadd<0x118, 0xf>(v);   // row_shr:8
  v = dppadd<0x142, 0xa>(v);   // row_bcast:15 -> rows 1,3
  v = dppadd<0x143, 0xc>(v);   // row_bcast:31 -> rows 2,3
  return v;
}
__device__ __forceinline__ float wsum(float v) {  // all-lanes result (step0 only)
  v += __shfl_xor(v, 1);  v += __shfl_xor(v, 2);  v += __shfl_xor(v, 4);
  v += __shfl_xor(v, 8);  v += __shfl_xor(v, 16); v += __shfl_xor(v, 32);
  return v;
}
__device__ __forceinline__ void gload16(const float* g, float* l) {
  __builtin_amdgcn_global_load_lds((const __attribute__((address_space(1))) uint32_t*)g,
                                   (__attribute__((address_space(3))) uint32_t*)l,
                                   16, 0, 0);
}
// barrier that drains LDS ops but lets global loads/stores ride (vmcnt untouched)
__device__ __forceinline__ void bar_lgkm() {
  asm volatile("s_waitcnt lgkmcnt(0)\n\ts_barrier" ::: "memory");
}
// truncation split: hi = top16(v) (exact trunc), lo = v - hi (exact), lo16 = top16(lo).
// v ~= hi + lo with relative error ~2^-16. ~4 VALU ops/element, no NaN fixup.
__device__ __forceinline__ void fsplit(const float (&v)[8], short8& hi, short8& lo) {
#pragma unroll
  for (int j = 0; j < 8; ++j) {
    uint32_t u = __float_as_uint(v[j]);
    hi[j] = (short)(u >> 16);
    float hf = __uint_as_float(u & 0xFFFF0000u);
    float lf = v[j] - hf;
    lo[j] = (short)(__float_as_uint(lf) >> 16);
  }
}
__device__ __forceinline__ void ldfragF(const float* p, short8& hi, short8& lo) {
  float4 a = *(const float4*)p, b = *(const float4*)(p + 4);
  float v[8] = {a.x,a.y,a.z,a.w,b.x,b.y,b.z,b.w};
  fsplit(v, hi, lo);
}
__device__ __forceinline__ f32x4 mfma3(short8 ah, short8 al, short8 bh, short8 bl,
                                       f32x4 acc) {
  acc = __builtin_amdgcn_mfma_f32_16x16x32_bf16(ah, bh, acc, 0, 0, 0);
  acc = __builtin_amdgcn_mfma_f32_16x16x32_bf16(al, bh, acc, 0, 0, 0);
  acc = __builtin_amdgcn_mfma_f32_16x16x32_bf16(ah, bl, acc, 0, 0, 0);
  return acc;
}
}  // namespace

// One block per batch element b. 512 threads = 8 waves, 4 ensemble rows/wave.
// R14 structure; this round: truncation-based bf16 split (4 ops/elem) and
// PRE-SPLIT bf16 hi/lo LDS staging for Mc (both layouts) + K^T, so MFMA
// B/A-fragments load directly as short8 (no per-use conversion).
__global__ __launch_bounds__(512, 1) void nlf_kernel(
    const float* __restrict__ m0p, const float* __restrict__ q0p,
    const float* __restrict__ qp,  const float* __restrict__ kp,
    const float* __restrict__ Kp,  const float* __restrict__ Ap,
    const float* __restrict__ wp0p, const float* __restrict__ wf0p,
    const float* __restrict__ wp1p, const float* __restrict__ wp2p,
    const float* __restrict__ wfp,  float* __restrict__ outp)
{
  __shared__ __align__(16) float z_s[S_*68];      // carry z' (z - mf)
  __shared__ __align__(16) float zn_s[S_*68];     // zn (P1->P2), then zp (P3a->P4)
  __shared__ __align__(16) float Mc_s[L_*36];     // M_c fp32 (w0 mctk, w4 mkm)
  __shared__ __align__(16) short McH_s[L_*40];    // M_c hi, l-major (80B rows)
  __shared__ __align__(16) short McL_s[L_*40];    // M_c lo
  __shared__ __align__(16) short McTH_s[S_*72];   // M_c hi, s-major (144B rows)
  __shared__ __align__(16) short McTL_s[S_*72];
  __shared__ __align__(16) short KtTH_s[R_*72];   // K^T hi, r-major (144B rows)
  __shared__ __align__(16) short KtTL_s[R_*72];
  __shared__ __align__(16) float uni[8*68];       // mp partials
  __shared__ __align__(16) float wp1b[2][S_*S_];
  __shared__ __align__(16) float wp2b[2][S_*L_];
  __shared__ __align__(16) float wf_s[S_*R_];
  __shared__ __align__(16) float Ktb[2][L_*R_];   // K double-buffer (l-major)
  __shared__ __align__(16) float KtT_s[R_*68];    // K^T fp32 (w1 C8 Gram)
  __shared__ __align__(16) float ktv_s[L_];       // k_t vector
  __shared__ __align__(16) float v1t_s[S_*R_];
  __shared__ __align__(16) float KM_s[S_*R_];     // (Mc^T K)[s][r]
  __shared__ __align__(16) float mkm_s[L_*R_];    // per-lam mkm (w4 -> all)
  __shared__ __align__(16) float M8_s[64];
  __shared__ __align__(16) float C8_s[64];
  __shared__ __align__(16) float tk_s[S_];        // Mc^T k_t
  __shared__ __align__(16) float mf_s[L_];
  __shared__ __align__(16) float qv_s[L_];
  __shared__ __align__(16) float qsv_s[L_];
  __shared__ __align__(16) float q0v_s[L_];

  const int tid = threadIdx.x;
  const int lam = tid & 63;
  const int w   = tid >> 6;
  const int b   = blockIdx.x;
  const int mtl = w >> 2, ntl = w & 3;      // MFMA tile coords (P1)
  const int cc  = lam & 15, gg = lam >> 4;  // MFMA lane coords

  const float q_r  = qp[lam];
  const float qs_r = sqrtf(q_r);
  const float q0_r = q0p[lam];
  const float m0_r = m0p[lam];
  if (tid < 64) { qv_s[tid] = q_r; qsv_s[tid] = qs_r; q0v_s[tid] = q0_r; }

  // ---- A^T fragments (static): B-op lane holds A[ntl*16+cc][kk*32+gg*8+j] ----
  short8 ABh[2], ABl[2];
  {
    const float* arow = Ap + (size_t)(ntl*16 + cc)*64;
#pragma unroll
    for (int kk = 0; kk < 2; ++kk)
      ldfragF(arow + kk*32 + gg*8, ABh[kk], ABl[kk]);
  }

  float Kreg[8];
  {
    const float* kb = Kp + (size_t)b*(L_*R_) + lam*R_;
    float4 ka = *(const float4*)kb, kb4 = *(const float4*)(kb+4);
    Kreg[0]=ka.x;Kreg[1]=ka.y;Kreg[2]=ka.z;Kreg[3]=ka.w;
    Kreg[4]=kb4.x;Kreg[5]=kb4.y;Kreg[6]=kb4.z;Kreg[7]=kb4.w;
  }
  float kt_r = kp[(size_t)b*L_ + lam];

  // ---- prologue async loads ----
  if (w == 0) {                       // wp1[0] -> wp1b[1]
#pragma unroll
    for (int m = 0; m < 4; ++m) {
      int f = m*256 + lam*4, s = f >> 5, c = f & 31;
      gload16(wp1p + ((size_t)s*B_ + b)*S_ + c, &wp1b[1][f]);
    }
  } else if (w == 1 || w == 2) {      // wp2[0] -> wp2b[1]
#pragma unroll
    for (int m = 0; m < 4; ++m) {
      int f = (w-1)*1024 + m*256 + lam*4, s = f >> 6, c = f & 63;
      gload16(wp2p + ((size_t)s*B_ + b)*L_ + c, &wp2b[1][f]);
    }
  } else if (w == 3) {                // wf0 -> wf_s ; K[0] -> Ktb[0]
    { int f = lam*4, s = f >> 3, c = f & 7;
      gload16(wf0p + ((size_t)s*B_ + b)*R_ + c, &wf_s[f]); }
#pragma unroll
    for (int m = 0; m < 2; ++m) {
      int f = m*256 + lam*4;
      gload16(Kp + (size_t)b*(L_*R_) + f, &Ktb[0][f]);
    }
  } else if (w == 4 || w == 5) {      // w_p0 -> wp2b[0]
#pragma unroll
    for (int m = 0; m < 4; ++m) {
      int f = (w-4)*1024 + m*256 + lam*4, s = f >> 6, c = f & 63;
      gload16(wp0p + ((size_t)s*B_ + b)*L_ + c, &wp2b[0][f]);
    }
  } else if (w == 6) {                // K[1] -> Ktb[1]
#pragma unroll
    for (int m = 0; m < 2; ++m) {
      int f = m*256 + lam*4;
      gload16(Kp + ((size_t)1*B_ + b)*(L_*R_) + f, &Ktb[1][f]);
    }
  }
  __syncthreads();

  // 8x8 SPD: C8_s -> M8_s = inv(C8) via in-register Cholesky (rows in lanes 0-7)
  auto chol8M8 = [&]() {
    const int i8 = lam & 7;
    float c8[8], rd8 = 0.0f;
#pragma unroll
    for (int k = 0; k < 8; ++k) c8[k] = C8_s[i8*8 + k];
#pragma unroll
    for (int j = 0; j < 8; ++j) {
      float dj = rdlane(c8[j], j);
      float rinv = rsqrtf(dj);
      if (i8 == j) rd8 = rinv;
      c8[j] *= rinv;
#pragma unroll
      for (int k = j+1; k < 8; ++k)
        c8[k] = fmaf(-rdlane(c8[j], k), c8[j], c8[k]);
    }
    float w8[8];
#pragma unroll
    for (int i = 0; i < 8; ++i) {
      float sacc = (i == i8) ? 1.0f : 0.0f;
#pragma unroll
      for (int k = 0; k < i; ++k)
        sacc = fmaf(-rdlane(c8[k], i), w8[k], sacc);
      w8[i] = sacc * rdlane(rd8, i);
    }
#pragma unroll
    for (int i = 0; i < 8; ++i) {
      float msum = 0.0f;
#pragma unroll
      for (int k = 0; k < 8; ++k)
        msum = fmaf(rdlane(w8[k], i), w8[k], msum);
      if (lam < 8) M8_s[i*8 + lam] = msum;
    }
  };

  // ================= step 0 =================
  {
    const float Pp = q0_r;
    const float h0 = m0_r / Pp + kt_r;
    if (w == 0) {
      const int r1 = lam >> 3, r2 = lam & 7;
      float acc = 0.0f;
#pragma unroll 4
      for (int l = 0; l < 64; ++l)
        acc = fmaf(Ktb[0][l*8 + r1] * q0v_s[l], Ktb[0][l*8 + r2], acc);
      C8_s[lam] = acc + (r1 == r2 ? 1.0f : 0.0f);
      chol8M8();
      float t8[8];
#pragma unroll
      for (int r = 0; r < 8; ++r) t8[r] = wsum(Pp * Kreg[r] * h0);
      float acc2 = 0.0f;
#pragma unroll
      for (int r1i = 0; r1i < 8; ++r1i) {
        float4 ma = *(const float4*)&M8_s[r1i*8];
        float4 mb = *(const float4*)&M8_s[r1i*8+4];
        float y = ma.x*t8[0]+ma.y*t8[1]+ma.z*t8[2]+ma.w*t8[3]
                + mb.x*t8[4]+mb.y*t8[5]+mb.z*t8[6]+mb.w*t8[7];
        acc2 = fmaf(Kreg[r1i], y, acc2);
      }
      float m0f = Pp*h0 - Pp*acc2;
      mf_s[lam] = m0f;
      outp[(size_t)b*L_ + lam] = m0f;
    }
    __syncthreads();

    const float qs0 = sqrtf(q0_r);
#pragma unroll
    for (int i = 0; i < 4; ++i) {
      const int s = 4*w + i;
      float zp = qs0 * wp2b[0][s*64 + lam];
      float v1[8];
#pragma unroll
      for (int r = 0; r < 8; ++r)
        v1[r] = wsum(Kreg[r] * zp) + wf_s[s*8 + r];
      float acc = 0.0f;
#pragma unroll
      for (int r1i = 0; r1i < 8; ++r1i) {
        float4 ma = *(const float4*)&M8_s[r1i*8];
        float4 mb = *(const float4*)&M8_s[r1i*8+4];
        float y = ma.x*v1[0]+ma.y*v1[1]+ma.z*v1[2]+ma.w*v1[3]
                + mb.x*v1[4]+mb.y*v1[5]+mb.z*v1[6]+mb.w*v1[7];
        acc = fmaf(Kreg[r1i], y, acc);
      }
      z_s[s*68 + lam] = zp - Pp*acc;   // z' excludes m_f (added in next dyn)
    }
  }
  __syncthreads();

  // ================= steps 1..T-1 =================
  for (int t = 1; t < T_; ++t) {
    const int cb = t & 1, nb = cb ^ 1;

    // per-lane K/k reload (global; used P4 + t8)
    {
      const float* kb = Kp + ((size_t)t*B_ + b)*(L_*R_) + lam*R_;
      float4 ka = *(const float4*)kb, kb4 = *(const float4*)(kb+4);
      Kreg[0]=ka.x;Kreg[1]=ka.y;Kreg[2]=ka.z;Kreg[3]=ka.w;
      Kreg[4]=kb4.x;Kreg[5]=kb4.y;Kreg[6]=kb4.z;Kreg[7]=kb4.w;
      kt_r = kp[((size_t)t*B_ + b)*L_ + lam];
    }
    if (w == 0) ktv_s[lam] = kt_r;

    // ---- P1 (MFMA): X = (z'+mf) @ A^T ; zn = (z'+mf) + 0.1*tanh(X) ----
    {
      f32x4 acc = {0.0f, 0.0f, 0.0f, 0.0f};
#pragma unroll
      for (int kk = 0; kk < 2; ++kk) {
        const int l0 = kk*32 + gg*8;
        const int row = mtl*16 + cc;
        float4 za = *(const float4*)&z_s[row*68 + l0];
        float4 zb = *(const float4*)&z_s[row*68 + l0 + 4];
        float4 ma4 = *(const float4*)&mf_s[l0];
        float4 mb4 = *(const float4*)&mf_s[l0 + 4];
        float z8[8] = {za.x+ma4.x, za.y+ma4.y, za.z+ma4.z, za.w+ma4.w,
                       zb.x+mb4.x, zb.y+mb4.y, zb.z+mb4.z, zb.w+mb4.w};
        short8 ah, al;
        fsplit(z8, ah, al);
        acc = __builtin_amdgcn_mfma_f32_16x16x32_bf16(ah, ABh[kk], acc, 0, 0, 0);
        acc = __builtin_amdgcn_mfma_f32_16x16x32_bf16(al, ABh[kk], acc, 0, 0, 0);
        acc = __builtin_amdgcn_mfma_f32_16x16x32_bf16(ah, ABl[kk], acc, 0, 0, 0);
      }
      const int lout = ntl*16 + cc;
      const float mfl = mf_s[lout];
      float psum = 0.0f;
#pragma unroll
      for (int r = 0; r < 4; ++r) {
        const int sr = mtl*16 + gg*4 + r;
        float x = acc[r];
        float e = __expf(2.0f*x);
        float tnh = 1.0f - 2.0f/(e + 1.0f);
        float zv = (z_s[sr*68 + lout] + mfl) + 0.1f*tnh;
        zn_s[sr*68 + lout] = zv;
        psum += zv;
      }
      uni[(mtl*4 + gg)*68 + lout] = psum;
    }
    bar_lgkm();  // B1

    // ---- P0: async prefetch; drains at B2 (syncthreads) ----
    if (w == 0) {
      if (t < T_-1) {
#pragma unroll
        for (int m = 0; m < 4; ++m) {
          int f = m*256 + lam*4, s = f >> 5, c = f & 31;
          gload16(wp1p + (((size_t)t*S_ + s)*B_ + b)*S_ + c, &wp1b[nb][f]);
        }
      }
    } else if (w == 1 || w == 2) {
      if (t < T_-1) {
#pragma unroll
        for (int m = 0; m < 4; ++m) {
          int f = (w-1)*1024 + m*256 + lam*4, s = f >> 6, c = f & 63;
          gload16(wp2p + (((size_t)t*S_ + s)*B_ + b)*L_ + c, &wp2b[nb][f]);
        }
      }
    } else if (w == 3) {
      { int f = lam*4, s = f >> 3, c = f & 7;
        gload16(wfp + (((size_t)(t-1)*S_ + s)*B_ + b)*R_ + c, &wf_s[f]); }
      if (t < T_-1) {
#pragma unroll
        for (int m = 0; m < 2; ++m) {
          int f = m*256 + lam*4;
          gload16(Kp + ((size_t)(t+1)*B_ + b)*(L_*R_) + f, &Ktb[nb][f]);
        }
      }
    }

    // ---- P2: m_p, Mc fp32 + bf16 staging (both layouts), KtT (w5) ----
    float mp = 0.0f;
#pragma unroll
    for (int ww = 0; ww < 8; ++ww) mp += uni[ww*68 + lam];
    mp *= 0.03125f;
    {
      short h4[4], l4[4];
#pragma unroll
      for (int i = 0; i < 4; ++i) {
        const int s = 4*w + i;
        float mcv = (zn_s[s*68 + lam] - mp) * 0.17677669529663689f;
        Mc_s[lam*36 + s] = mcv;
        uint32_t u = __float_as_uint(mcv);
        short hs = (short)(u >> 16);
        float hf = __uint_as_float(u & 0xFFFF0000u);
        short ls = (short)(__float_as_uint(mcv - hf) >> 16);
        h4[i] = hs; l4[i] = ls;
        McTH_s[s*72 + lam] = hs;
        McTL_s[s*72 + lam] = ls;
      }
      // packed b64 writes into l-major rows (cols 4w..4w+3)
      uint32_t hp0 = (uint32_t)(uint16_t)h4[0] | ((uint32_t)(uint16_t)h4[1] << 16);
      uint32_t hp1 = (uint32_t)(uint16_t)h4[2] | ((uint32_t)(uint16_t)h4[3] << 16);
      uint32_t lp0 = (uint32_t)(uint16_t)l4[0] | ((uint32_t)(uint16_t)l4[1] << 16);
      uint32_t lp1 = (uint32_t)(uint16_t)l4[2] | ((uint32_t)(uint16_t)l4[3] << 16);
      *(uint2*)&McH_s[lam*40 + 4*w] = make_uint2(hp0, hp1);
      *(uint2*)&McL_s[lam*40 + 4*w] = make_uint2(lp0, lp1);
    }
    if (w == 5) {   // KtT fp32 + bf16 hi/lo: KtT[r][l] = Ktb[cb][l][r]
      float4 a = *(const float4*)&Ktb[cb][lam*8];
      float4 c4 = *(const float4*)&Ktb[cb][lam*8+4];
      float kv[8] = {a.x,a.y,a.z,a.w,c4.x,c4.y,c4.z,c4.w};
#pragma unroll
      for (int r = 0; r < 8; ++r) {
        KtT_s[r*68 + lam] = kv[r];
        uint32_t u = __float_as_uint(kv[r]);
        short hs = (short)(u >> 16);
        float hf = __uint_as_float(u & 0xFFFF0000u);
        short ls = (short)(__float_as_uint(kv[r] - hf) >> 16);
        KtTH_s[r*72 + lam] = hs;
        KtTL_s[r*72 + lam] = ls;
      }
    }
    __syncthreads();  // B2 (full: drains prefetch vmcnt)

    // ---- P3a: zp tiles (w2-7) + KM|tk tiles (w0-1) ----
    if (w >= 2) {
      // zp[s][l] = sum_s2 wp1[s][s2]*Mc[l][s2]  (+ qs*wp2)
      auto zpTile = [&](int tl) {
        const int mt = tl >> 2, nt = tl & 3;
        short8 ah, al;
        ldfragF(&wp1b[cb][(mt*16+cc)*32 + gg*8], ah, al);
        short8 bh = *(const short8*)&McH_s[(nt*16+cc)*40 + gg*8];
        short8 bl = *(const short8*)&McL_s[(nt*16+cc)*40 + gg*8];
        f32x4 acc = {0,0,0,0};
        acc = mfma3(ah, al, bh, bl, acc);
        const int col = nt*16 + cc;
        const float qsc = qsv_s[col];
#pragma unroll
        for (int r = 0; r < 4; ++r) {
          const int row = mt*16 + gg*4 + r;
          zn_s[row*68 + col] = acc[r] + qsc * wp2b[cb][row*64 + col];
        }
      };
      if (w <= 5) zpTile(w - 2);
      else { zpTile(2*w - 8); zpTile(2*w - 7); }   // w6:{4,5} w7:{6,7}
    } else {
      // [KM | tk][s][c] = sum_l Mc[l][s] * [K[l][c] | kt[l]]
      const int mt = w;
      f32x4 acc = {0,0,0,0};
#pragma unroll
      for (int ks = 0; ks < 2; ++ks) {
        short8 ah = *(const short8*)&McTH_s[(mt*16+cc)*72 + ks*32 + gg*8];
        short8 al = *(const short8*)&McTL_s[(mt*16+cc)*72 + ks*32 + gg*8];
        short8 bh, bl;
        if (cc < 8) {
          bh = *(const short8*)&KtTH_s[cc*72 + ks*32 + gg*8];
          bl = *(const short8*)&KtTL_s[cc*72 + ks*32 + gg*8];
        } else if (cc == 8) {
          float bv[8];
#pragma unroll
          for (int j = 0; j < 8; ++j) bv[j] = ktv_s[ks*32 + gg*8 + j];
          fsplit(bv, bh, bl);
        } else {
          bh = short8{0,0,0,0,0,0,0,0}; bl = short8{0,0,0,0,0,0,0,0};
        }
        acc = mfma3(ah, al, bh, bl, acc);
      }
#pragma unroll
      for (int r = 0; r < 4; ++r) {
        const int s = mt*16 + gg*4 + r;
        if (cc < 8) KM_s[s*8 + cc] = acc[r];
        else if (cc == 8) tk_s[s] = acc[r];
      }
    }
    bar_lgkm();  // B2b (zp, KM, tk visible)

    // ---- P3b: v1t tiles (w2-3), C8+chol8 (w1), u+t8 (w0), mkm (w4) ----
    float u_r = 0.0f, t8s[8];
#pragma unroll
    for (int r = 0; r < 8; ++r) t8s[r] = 0.0f;
    if (w == 0) {
      float mctk = 0.0f;
#pragma unroll
      for (int s4 = 0; s4 < 32; s4 += 4) {
        float4 mc4 = *(const float4*)&Mc_s[lam*36 + s4];
        float4 tb  = *(const float4*)&tk_s[s4];
        mctk = fmaf(mc4.x, tb.x, mctk);
        mctk = fmaf(mc4.y, tb.y, mctk);
        mctk = fmaf(mc4.z, tb.z, mctk);
        mctk = fmaf(mc4.w, tb.w, mctk);
      }
      u_r = mp + mctk + q_r * kt_r;
#pragma unroll
      for (int r = 0; r < 8; ++r)
        t8s[r] = rdlane(wredsum(Kreg[r] * u_r), 63);
    } else if (w == 1) {
      const int r1 = lam >> 3, r2 = lam & 7;
      float acc = 0.0f;
#pragma unroll 4
      for (int s = 0; s < 32; ++s)
        acc = fmaf(KM_s[s*8 + r1], KM_s[s*8 + r2], acc);
#pragma unroll 4
      for (int l4 = 0; l4 < 64; l4 += 4) {
        float4 ka = *(const float4*)&KtT_s[r1*68 + l4];
        float4 kb = *(const float4*)&KtT_s[r2*68 + l4];
        float4 qv4 = *(const float4*)&qv_s[l4];
        acc = fmaf(ka.x*qv4.x, kb.x, acc);
        acc = fmaf(ka.y*qv4.y, kb.y, acc);
        acc = fmaf(ka.z*qv4.z, kb.z, acc);
        acc = fmaf(ka.w*qv4.w, kb.w, acc);
      }
      C8_s[lam] = acc + (r1 == r2 ? 1.0f : 0.0f);
      chol8M8();
    } else if (w == 2 || w == 3) {
      // v1t[s][r] = sum_l zp[s][l]*K[l][r] + wf
      const int mt = w - 2;
      f32x4 acc = {0,0,0,0};
#pragma unroll
      for (int ks = 0; ks < 2; ++ks) {
        short8 ah, al;
        ldfragF(&zn_s[(mt*16+cc)*68 + ks*32 + gg*8], ah, al);
        short8 bh, bl;
        if (cc < 8) {
          bh = *(const short8*)&KtTH_s[cc*72 + ks*32 + gg*8];
          bl = *(const short8*)&KtTL_s[cc*72 + ks*32 + gg*8];
        } else {
          bh = short8{0,0,0,0,0,0,0,0}; bl = short8{0,0,0,0,0,0,0,0};
        }
        acc = mfma3(ah, al, bh, bl, acc);
      }
#pragma unroll
      for (int r = 0; r < 4; ++r) {
        const int s = mt*16 + gg*4 + r;
        if (cc < 8) v1t_s[s*8 + cc] = acc[r] + wf_s[s*8 + cc];
      }
    } else if (w == 4) {
      // mkm[r] = sum_s2 Mc[lam][s2]*KM[s2][r]  (once; published for all)
      float mkm[8];
#pragma unroll
      for (int r = 0; r < 8; ++r) mkm[r] = 0.0f;
#pragma unroll
      for (int s4 = 0; s4 < 32; s4 += 4) {
        float4 mc4 = *(const float4*)&Mc_s[lam*36 + s4];
#pragma unroll
        for (int ii = 0; ii < 4; ++ii) {
          const float mcl = (ii==0)?mc4.x:(ii==1)?mc4.y:(ii==2)?mc4.z:mc4.w;
          float4 ka = *(const float4*)&KM_s[(s4+ii)*8];
          float4 kb = *(const float4*)&KM_s[(s4+ii)*8+4];
          mkm[0] = fmaf(mcl, ka.x, mkm[0]);
          mkm[1] = fmaf(mcl, ka.y, mkm[1]);
          mkm[2] = fmaf(mcl, ka.z, mkm[2]);
          mkm[3] = fmaf(mcl, ka.w, mkm[3]);
          mkm[4] = fmaf(mcl, kb.x, mkm[4]);
          mkm[5] = fmaf(mcl, kb.y, mkm[5]);
          mkm[6] = fmaf(mcl, kb.z, mkm[6]);
          mkm[7] = fmaf(mcl, kb.w, mkm[7]);
        }
      }
      *(float4*)&mkm_s[lam*8]   = make_float4(mkm[0],mkm[1],mkm[2],mkm[3]);
      *(float4*)&mkm_s[lam*8+4] = make_float4(mkm[4],mkm[5],mkm[6],mkm[7]);
    }
    bar_lgkm();  // B3 (M8_s, v1t_s, mkm_s visible)

    // ---- P4: fold M8 once per lane (symmetric): kM8 = M8 K, mkmM8 = M8 mkm ----
    float4 mk_a = *(const float4*)&mkm_s[lam*8];
    float4 mk_b = *(const float4*)&mkm_s[lam*8+4];
    const float mkmv[8] = {mk_a.x, mk_a.y, mk_a.z, mk_a.w,
                           mk_b.x, mk_b.y, mk_b.z, mk_b.w};
    float kM8[8], mkmM8[8];
#pragma unroll
    for (int j = 0; j < 8; ++j) { kM8[j] = 0.0f; mkmM8[j] = 0.0f; }
#pragma unroll
    for (int r = 0; r < 8; ++r) {
      float4 ma = *(const float4*)&M8_s[r*8];
      float4 mb = *(const float4*)&M8_s[r*8+4];
      const float kr = Kreg[r], mr = mkmv[r];
      kM8[0] = fmaf(kr, ma.x, kM8[0]);   mkmM8[0] = fmaf(mr, ma.x, mkmM8[0]);
      kM8[1] = fmaf(kr, ma.y, kM8[1]);   mkmM8[1] = fmaf(mr, ma.y, mkmM8[1]);
      kM8[2] = fmaf(kr, ma.z, kM8[2]);   mkmM8[2] = fmaf(mr, ma.z, mkmM8[2]);
      kM8[3] = fmaf(kr, ma.w, kM8[3]);   mkmM8[3] = fmaf(mr, ma.w, mkmM8[3]);
      kM8[4] = fmaf(kr, mb.x, kM8[4]);   mkmM8[4] = fmaf(mr, mb.x, mkmM8[4]);
      kM8[5] = fmaf(kr, mb.y, kM8[5]);   mkmM8[5] = fmaf(mr, mb.y, mkmM8[5]);
      kM8[6] = fmaf(kr, mb.z, kM8[6]);   mkmM8[6] = fmaf(mr, mb.z, mkmM8[6]);
      kM8[7] = fmaf(kr, mb.w, kM8[7]);   mkmM8[7] = fmaf(mr, mb.w, mkmM8[7]);
    }
#pragma unroll
    for (int i = 0; i < 4; ++i) {
      const int s = 4*w + i;
      float4 va = *(const float4*)&v1t_s[s*8];
      float4 vb = *(const float4*)&v1t_s[s*8+4];
      float g    = kM8[0]*va.x + kM8[1]*va.y + kM8[2]*va.z + kM8[3]*va.w
                 + kM8[4]*vb.x + kM8[5]*vb.y + kM8[6]*vb.z + kM8[7]*vb.w;
      float corr = mkmM8[0]*va.x + mkmM8[1]*va.y + mkmM8[2]*va.z + mkmM8[3]*va.w
                 + mkmM8[4]*vb.x + mkmM8[5]*vb.y + mkmM8[6]*vb.z + mkmM8[7]*vb.w;
      float zp = zn_s[s*68 + lam];
      z_s[s*68 + lam] = zp - corr - q_r*g;   // z' (mf added next dyn)
    }
    if (w == 0) {   // mf tail
      float g    = kM8[0]*t8s[0] + kM8[1]*t8s[1] + kM8[2]*t8s[2] + kM8[3]*t8s[3]
                 + kM8[4]*t8s[4] + kM8[5]*t8s[5] + kM8[6]*t8s[6] + kM8[7]*t8s[7];
      float corr = mkmM8[0]*t8s[0] + mkmM8[1]*t8s[1] + mkmM8[2]*t8s[2] + mkmM8[3]*t8s[3]
                 + mkmM8[4]*t8s[4] + mkmM8[5]*t8s[5] + mkmM8[6]*t8s[6] + mkmM8[7]*t8s[7];
      const float mf_r = u_r - corr - q_r*g;
      mf_s[lam] = mf_r;
      outp[((size_t)t*B_ + b)*L_ + lam] = mf_r;
    }
    bar_lgkm();  // B4 (mf_s, z_s visible for next P1)
  }
}

extern "C" void kernel_launch(void* const* d_in, const int* in_sizes, int n_in,
                              void* d_out, int out_size, void* d_ws, size_t ws_size,
                              hipStream_t stream) {
  (void)in_sizes; (void)n_in; (void)out_size; (void)d_ws; (void)ws_size;
  nlf_kernel<<<dim3(B_), dim3(512), 0, stream>>>(
      (const float*)d_in[0], (const float*)d_in[1], (const float*)d_in[2],
      (const float*)d_in[3], (const float*)d_in[4], (const float*)d_in[5],
      (const float*)d_in[6], (const float*)d_in[7], (const float*)d_in[8],
      (const float*)d_in[9], (const float*)d_in[10], (float*)d_out);
}

// Round 16
// 2580.771 us; speedup vs baseline: 2.4052x; 1.0345x over previous
//
#include <hip/hip_runtime.h>
#include <hip/hip_bf16.h>
#include <cstdint>
#include <cstddef>

namespace {
constexpr int T_ = 500, S_ = 32, B_ = 128, L_ = 64, R_ = 8;

typedef __attribute__((ext_vector_type(8))) short short8;
typedef __attribute__((ext_vector_type(4))) float f32x4;

__device__ __forceinline__ float rdlane(float v, int l) {
  return __int_as_float(__builtin_amdgcn_readlane(__float_as_int(v), l));
}
template<int CTRL, int RM>
__device__ __forceinline__ float dppadd(float v) {
  int t = __builtin_amdgcn_update_dpp(0, __float_as_int(v), CTRL, RM, 0xf, false);
  return v + __int_as_float(t);
}
__device__ __forceinline__ float wredsum(float v) {
  v = dppadd<0x111, 0xf>(v);
  v = dppadd<0x112, 0xf>(v);
  v = dppadd<0x114, 0xf>(v);
  v = dppadd<0x118, 0xf>(v);
  v = dppadd<0x142, 0xa>(v);
  v = dppadd<0x143, 0xc>(v);
  return v;
}
__device__ __forceinline__ float wsum(float v) {
  v += __shfl_xor(v, 1);  v += __shfl_xor(v, 2);  v += __shfl_xor(v, 4);
  v += __shfl_xor(v, 8);  v += __shfl_xor(v, 16); v += __shfl_xor(v, 32);
  return v;
}
__device__ __forceinline__ void gload16(const float* g, float* l) {
  __builtin_amdgcn_global_load_lds((const __attribute__((address_space(1))) uint32_t*)g,
                                   (__attribute__((address_space(3))) uint32_t*)l,
                                   16, 0, 0);
}
// barrier draining LDS only (global loads stay in flight)
__device__ __forceinline__ void bar_lgkm() {
  asm volatile("s_waitcnt lgkmcnt(0)\n\ts_barrier" ::: "memory");
}
// barrier draining LDS + all vector-memory (fences the async prefetches)
__device__ __forceinline__ void barV() {
  asm volatile("s_waitcnt vmcnt(0) lgkmcnt(0)\n\ts_barrier" ::: "memory");
}
// truncation split: v ~= hi + lo, rel err ~2^-16, ~4 VALU ops/element.
__device__ __forceinline__ void fsplit(const float (&v)[8], short8& hi, short8& lo) {
#pragma unroll
  for (int j = 0; j < 8; ++j) {
    uint32_t u = __float_as_uint(v[j]);
    hi[j] = (short)(u >> 16);
    float hf = __uint_as_float(u & 0xFFFF0000u);
    float lf = v[j] - hf;
    lo[j] = (short)(__float_as_uint(lf) >> 16);
  }
}
__device__ __forceinline__ void ldfragF(const float* p, short8& hi, short8& lo) {
  float4 a = *(const float4*)p, b = *(const float4*)(p + 4);
  float v[8] = {a.x,a.y,a.z,a.w,b.x,b.y,b.z,b.w};
  fsplit(v, hi, lo);
}
__device__ __forceinline__ f32x4 mfma3(short8 ah, short8 al, short8 bh, short8 bl,
                                       f32x4 acc) {
  acc = __builtin_amdgcn_mfma_f32_16x16x32_bf16(ah, bh, acc, 0, 0, 0);
  acc = __builtin_amdgcn_mfma_f32_16x16x32_bf16(al, bh, acc, 0, 0, 0);
  acc = __builtin_amdgcn_mfma_f32_16x16x32_bf16(ah, bl, acc, 0, 0, 0);
  return acc;
}
}  // namespace

// One block per batch element b. 512 threads = 8 waves, 4 ensemble rows/wave.
// R15 structure; this round:
//  - prefetch issues moved AFTER B2; B2 no longer drains vmcnt (bar_lgkm),
//    B4 fences vmcnt (barV) ~2.5k cycles after issue -> loads get a full
//    step in flight instead of ~300 cycles (kills the per-step B2 stall).
//  - wf double-buffered (wfb[2]) so it too is a next-step prefetch.
//  - KMT_s staging: w1's C8 KM-Gram reads 16 b128 instead of 64 scalar LDS.
__global__ __launch_bounds__(512, 1) void nlf_kernel(
    const float* __restrict__ m0p, const float* __restrict__ q0p,
    const float* __restrict__ qp,  const float* __restrict__ kp,
    const float* __restrict__ Kp,  const float* __restrict__ Ap,
    const float* __restrict__ wp0p, const float* __restrict__ wf0p,
    const float* __restrict__ wp1p, const float* __restrict__ wp2p,
    const float* __restrict__ wfp,  float* __restrict__ outp)
{
  __shared__ __align__(16) float z_s[S_*68];      // carry z' (z - mf)
  __shared__ __align__(16) float zn_s[S_*68];     // zn (P1->P2), then zp (P3a->P4)
  __shared__ __align__(16) float Mc_s[L_*36];     // M_c fp32 (w0 mctk, w4 mkm)
  __shared__ __align__(16) short McH_s[L_*40];    // M_c hi, l-major
  __shared__ __align__(16) short McL_s[L_*40];    // M_c lo
  __shared__ __align__(16) short McTH_s[S_*72];   // M_c hi, s-major
  __shared__ __align__(16) short McTL_s[S_*72];
  __shared__ __align__(16) short KtTH_s[R_*72];   // K^T hi, r-major
  __shared__ __align__(16) short KtTL_s[R_*72];
  __shared__ __align__(16) float uni[8*68];       // mp partials
  __shared__ __align__(16) float wp1b[2][S_*S_];
  __shared__ __align__(16) float wp2b[2][S_*L_];
  __shared__ __align__(16) float wfb[2][S_*R_];   // wf double-buffer
  __shared__ __align__(16) float Ktb[2][L_*R_];   // K double-buffer (l-major)
  __shared__ __align__(16) float KtT_s[R_*68];    // K^T fp32 (w1 C8 q-Gram)
  __shared__ __align__(16) float ktv_s[L_];       // k_t vector
  __shared__ __align__(16) float v1t_s[S_*R_];
  __shared__ __align__(16) float KM_s[S_*R_];     // (Mc^T K)[s][r]
  __shared__ __align__(16) float KMT_s[R_*36];    // (Mc^T K)^T [r][s]
  __shared__ __align__(16) float mkm_s[L_*R_];    // per-lam mkm (w4 -> all)
  __shared__ __align__(16) float M8_s[64];
  __shared__ __align__(16) float C8_s[64];
  __shared__ __align__(16) float tk_s[S_];        // Mc^T k_t
  __shared__ __align__(16) float mf_s[L_];
  __shared__ __align__(16) float qv_s[L_];
  __shared__ __align__(16) float qsv_s[L_];
  __shared__ __align__(16) float q0v_s[L_];

  const int tid = threadIdx.x;
  const int lam = tid & 63;
  const int w   = tid >> 6;
  const int b   = blockIdx.x;
  const int mtl = w >> 2, ntl = w & 3;      // MFMA tile coords (P1)
  const int cc  = lam & 15, gg = lam >> 4;  // MFMA lane coords

  const float q_r  = qp[lam];
  const float qs_r = sqrtf(q_r);
  const float q0_r = q0p[lam];
  const float m0_r = m0p[lam];
  if (tid < 64) { qv_s[tid] = q_r; qsv_s[tid] = qs_r; q0v_s[tid] = q0_r; }

  // ---- A^T fragments (static) ----
  short8 ABh[2], ABl[2];
  {
    const float* arow = Ap + (size_t)(ntl*16 + cc)*64;
#pragma unroll
    for (int kk = 0; kk < 2; ++kk)
      ldfragF(arow + kk*32 + gg*8, ABh[kk], ABl[kk]);
  }

  float Kreg[8];
  {
    const float* kb = Kp + (size_t)b*(L_*R_) + lam*R_;
    float4 ka = *(const float4*)kb, kb4 = *(const float4*)(kb+4);
    Kreg[0]=ka.x;Kreg[1]=ka.y;Kreg[2]=ka.z;Kreg[3]=ka.w;
    Kreg[4]=kb4.x;Kreg[5]=kb4.y;Kreg[6]=kb4.z;Kreg[7]=kb4.w;
  }
  float kt_r = kp[(size_t)b*L_ + lam];

  // ---- prologue async loads ----
  if (w == 0) {                       // wp1[0] -> wp1b[1]
#pragma unroll
    for (int m = 0; m < 4; ++m) {
      int f = m*256 + lam*4, s = f >> 5, c = f & 31;
      gload16(wp1p + ((size_t)s*B_ + b)*S_ + c, &wp1b[1][f]);
    }
  } else if (w == 1 || w == 2) {      // wp2[0] -> wp2b[1]
#pragma unroll
    for (int m = 0; m < 4; ++m) {
      int f = (w-1)*1024 + m*256 + lam*4, s = f >> 6, c = f & 63;
      gload16(wp2p + ((size_t)s*B_ + b)*L_ + c, &wp2b[1][f]);
    }
  } else if (w == 3) {                // wf0 -> wfb[0] ; K[0] -> Ktb[0]
    { int f = lam*4, s = f >> 3, c = f & 7;
      gload16(wf0p + ((size_t)s*B_ + b)*R_ + c, &wfb[0][f]); }
#pragma unroll
    for (int m = 0; m < 2; ++m) {
      int f = m*256 + lam*4;
      gload16(Kp + (size_t)b*(L_*R_) + f, &Ktb[0][f]);
    }
  } else if (w == 4 || w == 5) {      // w_p0 -> wp2b[0]
#pragma unroll
    for (int m = 0; m < 4; ++m) {
      int f = (w-4)*1024 + m*256 + lam*4, s = f >> 6, c = f & 63;
      gload16(wp0p + ((size_t)s*B_ + b)*L_ + c, &wp2b[0][f]);
    }
  } else if (w == 6) {                // K[1] -> Ktb[1]
#pragma unroll
    for (int m = 0; m < 2; ++m) {
      int f = m*256 + lam*4;
      gload16(Kp + ((size_t)1*B_ + b)*(L_*R_) + f, &Ktb[1][f]);
    }
  } else if (w == 7) {                // wf[0] -> wfb[1] (for step 1)
    int f = lam*4, s = f >> 3, c = f & 7;
    gload16(wfp + ((size_t)s*B_ + b)*R_ + c, &wfb[1][f]);
  }
  __syncthreads();

  // 8x8 SPD: C8_s -> M8_s = inv(C8) via in-register Cholesky (rows in lanes 0-7)
  auto chol8M8 = [&]() {
    const int i8 = lam & 7;
    float c8[8], rd8 = 0.0f;
#pragma unroll
    for (int k = 0; k < 8; ++k) c8[k] = C8_s[i8*8 + k];
#pragma unroll
    for (int j = 0; j < 8; ++j) {
      float dj = rdlane(c8[j], j);
      float rinv = rsqrtf(dj);
      if (i8 == j) rd8 = rinv;
      c8[j] *= rinv;
#pragma unroll
      for (int k = j+1; k < 8; ++k)
        c8[k] = fmaf(-rdlane(c8[j], k), c8[j], c8[k]);
    }
    float w8[8];
#pragma unroll
    for (int i = 0; i < 8; ++i) {
      float sacc = (i == i8) ? 1.0f : 0.0f;
#pragma unroll
      for (int k = 0; k < i; ++k)
        sacc = fmaf(-rdlane(c8[k], i), w8[k], sacc);
      w8[i] = sacc * rdlane(rd8, i);
    }
#pragma unroll
    for (int i = 0; i < 8; ++i) {
      float msum = 0.0f;
#pragma unroll
      for (int k = 0; k < 8; ++k)
        msum = fmaf(rdlane(w8[k], i), w8[k], msum);
      if (lam < 8) M8_s[i*8 + lam] = msum;
    }
  };

  // ================= step 0 =================
  {
    const float Pp = q0_r;
    const float h0 = m0_r / Pp + kt_r;
    if (w == 0) {
      const int r1 = lam >> 3, r2 = lam & 7;
      float acc = 0.0f;
#pragma unroll 4
      for (int l = 0; l < 64; ++l)
        acc = fmaf(Ktb[0][l*8 + r1] * q0v_s[l], Ktb[0][l*8 + r2], acc);
      C8_s[lam] = acc + (r1 == r2 ? 1.0f : 0.0f);
      chol8M8();
      float t8[8];
#pragma unroll
      for (int r = 0; r < 8; ++r) t8[r] = wsum(Pp * Kreg[r] * h0);
      float acc2 = 0.0f;
#pragma unroll
      for (int r1i = 0; r1i < 8; ++r1i) {
        float4 ma = *(const float4*)&M8_s[r1i*8];
        float4 mb = *(const float4*)&M8_s[r1i*8+4];
        float y = ma.x*t8[0]+ma.y*t8[1]+ma.z*t8[2]+ma.w*t8[3]
                + mb.x*t8[4]+mb.y*t8[5]+mb.z*t8[6]+mb.w*t8[7];
        acc2 = fmaf(Kreg[r1i], y, acc2);
      }
      float m0f = Pp*h0 - Pp*acc2;
      mf_s[lam] = m0f;
      outp[(size_t)b*L_ + lam] = m0f;
    }
    __syncthreads();

    const float qs0 = sqrtf(q0_r);
#pragma unroll
    for (int i = 0; i < 4; ++i) {
      const int s = 4*w + i;
      float zp = qs0 * wp2b[0][s*64 + lam];
      float v1[8];
#pragma unroll
      for (int r = 0; r < 8; ++r)
        v1[r] = wsum(Kreg[r] * zp) + wfb[0][s*8 + r];
      float acc = 0.0f;
#pragma unroll
      for (int r1i = 0; r1i < 8; ++r1i) {
        float4 ma = *(const float4*)&M8_s[r1i*8];
        float4 mb = *(const float4*)&M8_s[r1i*8+4];
        float y = ma.x*v1[0]+ma.y*v1[1]+ma.z*v1[2]+ma.w*v1[3]
                + mb.x*v1[4]+mb.y*v1[5]+mb.z*v1[6]+mb.w*v1[7];
        acc = fmaf(Kreg[r1i], y, acc);
      }
      z_s[s*68 + lam] = zp - Pp*acc;   // z' excludes m_f (added in next dyn)
    }
  }
  __syncthreads();

  // ================= steps 1..T-1 =================
  for (int t = 1; t < T_; ++t) {
    const int cb = t & 1, nb = cb ^ 1;

    // per-lane K/k reload (global; used P3b/P4)
    {
      const float* kb = Kp + ((size_t)t*B_ + b)*(L_*R_) + lam*R_;
      float4 ka = *(const float4*)kb, kb4 = *(const float4*)(kb+4);
      Kreg[0]=ka.x;Kreg[1]=ka.y;Kreg[2]=ka.z;Kreg[3]=ka.w;
      Kreg[4]=kb4.x;Kreg[5]=kb4.y;Kreg[6]=kb4.z;Kreg[7]=kb4.w;
      kt_r = kp[((size_t)t*B_ + b)*L_ + lam];
    }
    if (w == 0) ktv_s[lam] = kt_r;

    // ---- P1 (MFMA): X = (z'+mf) @ A^T ; zn = (z'+mf) + 0.1*tanh(X) ----
    {
      f32x4 acc = {0.0f, 0.0f, 0.0f, 0.0f};
#pragma unroll
      for (int kk = 0; kk < 2; ++kk) {
        const int l0 = kk*32 + gg*8;
        const int row = mtl*16 + cc;
        float4 za = *(const float4*)&z_s[row*68 + l0];
        float4 zb = *(const float4*)&z_s[row*68 + l0 + 4];
        float4 ma4 = *(const float4*)&mf_s[l0];
        float4 mb4 = *(const float4*)&mf_s[l0 + 4];
        float z8[8] = {za.x+ma4.x, za.y+ma4.y, za.z+ma4.z, za.w+ma4.w,
                       zb.x+mb4.x, zb.y+mb4.y, zb.z+mb4.z, zb.w+mb4.w};
        short8 ah, al;
        fsplit(z8, ah, al);
        acc = __builtin_amdgcn_mfma_f32_16x16x32_bf16(ah, ABh[kk], acc, 0, 0, 0);
        acc = __builtin_amdgcn_mfma_f32_16x16x32_bf16(al, ABh[kk], acc, 0, 0, 0);
        acc = __builtin_amdgcn_mfma_f32_16x16x32_bf16(ah, ABl[kk], acc, 0, 0, 0);
      }
      const int lout = ntl*16 + cc;
      const float mfl = mf_s[lout];
      float psum = 0.0f;
#pragma unroll
      for (int r = 0; r < 4; ++r) {
        const int sr = mtl*16 + gg*4 + r;
        float x = acc[r];
        float e = __expf(2.0f*x);
        float tnh = 1.0f - 2.0f/(e + 1.0f);
        float zv = (z_s[sr*68 + lout] + mfl) + 0.1f*tnh;
        zn_s[sr*68 + lout] = zv;
        psum += zv;
      }
      uni[(mtl*4 + gg)*68 + lout] = psum;
    }
    bar_lgkm();  // B1

    // ---- P2: m_p, Mc fp32 + bf16 staging (both layouts), KtT (w5) ----
    float mp = 0.0f;
#pragma unroll
    for (int ww = 0; ww < 8; ++ww) mp += uni[ww*68 + lam];
    mp *= 0.03125f;
    {
      short h4[4], l4[4];
#pragma unroll
      for (int i = 0; i < 4; ++i) {
        const int s = 4*w + i;
        float mcv = (zn_s[s*68 + lam] - mp) * 0.17677669529663689f;
        Mc_s[lam*36 + s] = mcv;
        uint32_t u = __float_as_uint(mcv);
        short hs = (short)(u >> 16);
        float hf = __uint_as_float(u & 0xFFFF0000u);
        short ls = (short)(__float_as_uint(mcv - hf) >> 16);
        h4[i] = hs; l4[i] = ls;
        McTH_s[s*72 + lam] = hs;
        McTL_s[s*72 + lam] = ls;
      }
      uint32_t hp0 = (uint32_t)(uint16_t)h4[0] | ((uint32_t)(uint16_t)h4[1] << 16);
      uint32_t hp1 = (uint32_t)(uint16_t)h4[2] | ((uint32_t)(uint16_t)h4[3] << 16);
      uint32_t lp0 = (uint32_t)(uint16_t)l4[0] | ((uint32_t)(uint16_t)l4[1] << 16);
      uint32_t lp1 = (uint32_t)(uint16_t)l4[2] | ((uint32_t)(uint16_t)l4[3] << 16);
      *(uint2*)&McH_s[lam*40 + 4*w] = make_uint2(hp0, hp1);
      *(uint2*)&McL_s[lam*40 + 4*w] = make_uint2(lp0, lp1);
    }
    if (w == 5) {   // KtT fp32 + bf16 hi/lo: KtT[r][l] = Ktb[cb][l][r]
      float4 a = *(const float4*)&Ktb[cb][lam*8];
      float4 c4 = *(const float4*)&Ktb[cb][lam*8+4];
      float kv[8] = {a.x,a.y,a.z,a.w,c4.x,c4.y,c4.z,c4.w};
#pragma unroll
      for (int r = 0; r < 8; ++r) {
        KtT_s[r*68 + lam] = kv[r];
        uint32_t u = __float_as_uint(kv[r]);
        short hs = (short)(u >> 16);
        float hf = __uint_as_float(u & 0xFFFF0000u);
        short ls = (short)(__float_as_uint(kv[r] - hf) >> 16);
        KtTH_s[r*72 + lam] = hs;
        KtTL_s[r*72 + lam] = ls;
      }
    }
    bar_lgkm();  // B2 (LDS only -- prefetches from last step already fenced at B4)

    // ---- P0': async prefetch for step t+1 (fenced at B4, used after next B2) ----
    if (t < T_-1) {
      if (w == 0) {
#pragma unroll
        for (int m = 0; m < 4; ++m) {
          int f = m*256 + lam*4, s = f >> 5, c = f & 31;
          gload16(wp1p + (((size_t)t*S_ + s)*B_ + b)*S_ + c, &wp1b[nb][f]);
        }
      } else if (w == 1 || w == 2) {
#pragma unroll
        for (int m = 0; m < 4; ++m) {
          int f = (w-1)*1024 + m*256 + lam*4, s = f >> 6, c = f & 63;
          gload16(wp2p + (((size_t)t*S_ + s)*B_ + b)*L_ + c, &wp2b[nb][f]);
        }
      } else if (w == 3) {
        { int f = lam*4, s = f >> 3, c = f & 7;
          gload16(wfp + (((size_t)t*S_ + s)*B_ + b)*R_ + c, &wfb[nb][f]); }
#pragma unroll
        for (int m = 0; m < 2; ++m) {
          int f = m*256 + lam*4;
          gload16(Kp + ((size_t)(t+1)*B_ + b)*(L_*R_) + f, &Ktb[nb][f]);
        }
      }
    }

    // ---- P3a: zp tiles (w2-7) + KM|tk tiles (w0-1, + KMT staging) ----
    if (w >= 2) {
      auto zpTile = [&](int tl) {
        const int mt = tl >> 2, nt = tl & 3;
        short8 ah, al;
        ldfragF(&wp1b[cb][(mt*16+cc)*32 + gg*8], ah, al);
        short8 bh = *(const short8*)&McH_s[(nt*16+cc)*40 + gg*8];
        short8 bl = *(const short8*)&McL_s[(nt*16+cc)*40 + gg*8];
        f32x4 acc = {0,0,0,0};
        acc = mfma3(ah, al, bh, bl, acc);
        const int col = nt*16 + cc;
        const float qsc = qsv_s[col];
#pragma unroll
        for (int r = 0; r < 4; ++r) {
          const int row = mt*16 + gg*4 + r;
          zn_s[row*68 + col] = acc[r] + qsc * wp2b[cb][row*64 + col];
        }
      };
      if (w <= 5) zpTile(w - 2);
      else { zpTile(2*w - 8); zpTile(2*w - 7); }   // w6:{4,5} w7:{6,7}
    } else {
      // [KM | tk][s][c] = sum_l Mc[l][s] * [K[l][c] | kt[l]]
      const int mt = w;
      f32x4 acc = {0,0,0,0};
#pragma unroll
      for (int ks = 0; ks < 2; ++ks) {
        short8 ah = *(const short8*)&McTH_s[(mt*16+cc)*72 + ks*32 + gg*8];
        short8 al = *(const short8*)&McTL_s[(mt*16+cc)*72 + ks*32 + gg*8];
        short8 bh, bl;
        if (cc < 8) {
          bh = *(const short8*)&KtTH_s[cc*72 + ks*32 + gg*8];
          bl = *(const short8*)&KtTL_s[cc*72 + ks*32 + gg*8];
        } else if (cc == 8) {
          float bv[8];
#pragma unroll
          for (int j = 0; j < 8; ++j) bv[j] = ktv_s[ks*32 + gg*8 + j];
          fsplit(bv, bh, bl);
        } else {
          bh = short8{0,0,0,0,0,0,0,0}; bl = short8{0,0,0,0,0,0,0,0};
        }
        acc = mfma3(ah, al, bh, bl, acc);
      }
#pragma unroll
      for (int r = 0; r < 4; ++r) {
        const int s = mt*16 + gg*4 + r;
        if (cc < 8) { KM_s[s*8 + cc] = acc[r]; KMT_s[cc*36 + s] = acc[r]; }
        else if (cc == 8) tk_s[s] = acc[r];
      }
    }
    bar_lgkm();  // B2b (zp, KM, KMT, tk visible)

    // ---- P3b: v1t tiles (w2-3), C8+chol8 (w1), u+t8 (w0), mkm (w4) ----
    float u_r = 0.0f, t8s[8];
#pragma unroll
    for (int r = 0; r < 8; ++r) t8s[r] = 0.0f;
    if (w == 0) {
      float mctk = 0.0f;
#pragma unroll
      for (int s4 = 0; s4 < 32; s4 += 4) {
        float4 mc4 = *(const float4*)&Mc_s[lam*36 + s4];
        float4 tb  = *(const float4*)&tk_s[s4];
        mctk = fmaf(mc4.x, tb.x, mctk);
        mctk = fmaf(mc4.y, tb.y, mctk);
        mctk = fmaf(mc4.z, tb.z, mctk);
        mctk = fmaf(mc4.w, tb.w, mctk);
      }
      u_r = mp + mctk + q_r * kt_r;
#pragma unroll
      for (int r = 0; r < 8; ++r)
        t8s[r] = rdlane(wredsum(Kreg[r] * u_r), 63);
    } else if (w == 1) {
      const int r1 = lam >> 3, r2 = lam & 7;
      float acc = 0.0f;
#pragma unroll
      for (int s4 = 0; s4 < 32; s4 += 4) {     // KM-Gram via KMT b128 rows
        float4 ka = *(const float4*)&KMT_s[r1*36 + s4];
        float4 kb = *(const float4*)&KMT_s[r2*36 + s4];
        acc = fmaf(ka.x, kb.x, acc);
        acc = fmaf(ka.y, kb.y, acc);
        acc = fmaf(ka.z, kb.z, acc);
        acc = fmaf(ka.w, kb.w, acc);
      }
#pragma unroll 4
      for (int l4 = 0; l4 < 64; l4 += 4) {     // q-Gram via KtT b128 rows
        float4 ka = *(const float4*)&KtT_s[r1*68 + l4];
        float4 kb = *(const float4*)&KtT_s[r2*68 + l4];
        float4 qv4 = *(const float4*)&qv_s[l4];
        acc = fmaf(ka.x*qv4.x, kb.x, acc);
        acc = fmaf(ka.y*qv4.y, kb.y, acc);
        acc = fmaf(ka.z*qv4.z, kb.z, acc);
        acc = fmaf(ka.w*qv4.w, kb.w, acc);
      }
      C8_s[lam] = acc + (r1 == r2 ? 1.0f : 0.0f);
      chol8M8();
    } else if (w == 2 || w == 3) {
      // v1t[s][r] = sum_l zp[s][l]*K[l][r] + wf
      const int mt = w - 2;
      f32x4 acc = {0,0,0,0};
#pragma unroll
      for (int ks = 0; ks < 2; ++ks) {
        short8 ah, al;
        ldfragF(&zn_s[(mt*16+cc)*68 + ks*32 + gg*8], ah, al);
        short8 bh, bl;
        if (cc < 8) {
          bh = *(const short8*)&KtTH_s[cc*72 + ks*32 + gg*8];
          bl = *(const short8*)&KtTL_s[cc*72 + ks*32 + gg*8];
        } else {
          bh = short8{0,0,0,0,0,0,0,0}; bl = short8{0,0,0,0,0,0,0,0};
        }
        acc = mfma3(ah, al, bh, bl, acc);
      }
#pragma unroll
      for (int r = 0; r < 4; ++r) {
        const int s = mt*16 + gg*4 + r;
        if (cc < 8) v1t_s[s*8 + cc] = acc[r] + wfb[cb][s*8 + cc];
      }
    } else if (w == 4) {
      // mkm[r] = sum_s2 Mc[lam][s2]*KM[s2][r]  (once; published for all)
      float mkm[8];
#pragma unroll
      for (int r = 0; r < 8; ++r) mkm[r] = 0.0f;
#pragma unroll
      for (int s4 = 0; s4 < 32; s4 += 4) {
        float4 mc4 = *(const float4*)&Mc_s[lam*36 + s4];
#pragma unroll
        for (int ii = 0; ii < 4; ++ii) {
          const float mcl = (ii==0)?mc4.x:(ii==1)?mc4.y:(ii==2)?mc4.z:mc4.w;
          float4 ka = *(const float4*)&KM_s[(s4+ii)*8];
          float4 kb = *(const float4*)&KM_s[(s4+ii)*8+4];
          mkm[0] = fmaf(mcl, ka.x, mkm[0]);
          mkm[1] = fmaf(mcl, ka.y, mkm[1]);
          mkm[2] = fmaf(mcl, ka.z, mkm[2]);
          mkm[3] = fmaf(mcl, ka.w, mkm[3]);
          mkm[4] = fmaf(mcl, kb.x, mkm[4]);
          mkm[5] = fmaf(mcl, kb.y, mkm[5]);
          mkm[6] = fmaf(mcl, kb.z, mkm[6]);
          mkm[7] = fmaf(mcl, kb.w, mkm[7]);
        }
      }
      *(float4*)&mkm_s[lam*8]   = make_float4(mkm[0],mkm[1],mkm[2],mkm[3]);
      *(float4*)&mkm_s[lam*8+4] = make_float4(mkm[4],mkm[5],mkm[6],mkm[7]);
    }
    bar_lgkm();  // B3 (M8_s, v1t_s, mkm_s visible)

    // ---- P4: fold M8 once per lane (symmetric): kM8 = M8 K, mkmM8 = M8 mkm ----
    float4 mk_a = *(const float4*)&mkm_s[lam*8];
    float4 mk_b = *(const float4*)&mkm_s[lam*8+4];
    const float mkmv[8] = {mk_a.x, mk_a.y, mk_a.z, mk_a.w,
                           mk_b.x, mk_b.y, mk_b.z, mk_b.w};
    float kM8[8], mkmM8[8];
#pragma unroll
    for (int j = 0; j < 8; ++j) { kM8[j] = 0.0f; mkmM8[j] = 0.0f; }
#pragma unroll
    for (int r = 0; r < 8; ++r) {
      float4 ma = *(const float4*)&M8_s[r*8];
      float4 mb = *(const float4*)&M8_s[r*8+4];
      const float kr = Kreg[r], mr = mkmv[r];
      kM8[0] = fmaf(kr, ma.x, kM8[0]);   mkmM8[0] = fmaf(mr, ma.x, mkmM8[0]);
      kM8[1] = fmaf(kr, ma.y, kM8[1]);   mkmM8[1] = fmaf(mr, ma.y, mkmM8[1]);
      kM8[2] = fmaf(kr, ma.z, kM8[2]);   mkmM8[2] = fmaf(mr, ma.z, mkmM8[2]);
      kM8[3] = fmaf(kr, ma.w, kM8[3]);   mkmM8[3] = fmaf(mr, ma.w, mkmM8[3]);
      kM8[4] = fmaf(kr, mb.x, kM8[4]);   mkmM8[4] = fmaf(mr, mb.x, mkmM8[4]);
      kM8[5] = fmaf(kr, mb.y, kM8[5]);   mkmM8[5] = fmaf(mr, mb.y, mkmM8[5]);
      kM8[6] = fmaf(kr, mb.z, kM8[6]);   mkmM8[6] = fmaf(mr, mb.z, mkmM8[6]);
      kM8[7] = fmaf(kr, mb.w, kM8[7]);   mkmM8[7] = fmaf(mr, mb.w, mkmM8[7]);
    }
#pragma unroll
    for (int i = 0; i < 4; ++i) {
      const int s = 4*w + i;
      float4 va = *(const float4*)&v1t_s[s*8];
      float4 vb = *(const float4*)&v1t_s[s*8+4];
      float g    = kM8[0]*va.x + kM8[1]*va.y + kM8[2]*va.z + kM8[3]*va.w
                 + kM8[4]*vb.x + kM8[5]*vb.y + kM8[6]*vb.z + kM8[7]*vb.w;
      float corr = mkmM8[0]*va.x + mkmM8[1]*va.y + mkmM8[2]*va.z + mkmM8[3]*va.w
                 + mkmM8[4]*vb.x + mkmM8[5]*vb.y + mkmM8[6]*vb.z + mkmM8[7]*vb.w;
      float zp = zn_s[s*68 + lam];
      z_s[s*68 + lam] = zp - corr - q_r*g;   // z' (mf added next dyn)
    }
    if (w == 0) {   // mf tail
      float g    = kM8[0]*t8s[0] + kM8[1]*t8s[1] + kM8[2]*t8s[2] + kM8[3]*t8s[3]
                 + kM8[4]*t8s[4] + kM8[5]*t8s[5] + kM8[6]*t8s[6] + kM8[7]*t8s[7];
      float corr = mkmM8[0]*t8s[0] + mkmM8[1]*t8s[1] + mkmM8[2]*t8s[2] + mkmM8[3]*t8s[3]
                 + mkmM8[4]*t8s[4] + mkmM8[5]*t8s[5] + mkmM8[6]*t8s[6] + mkmM8[7]*t8s[7];
      const float mf_r = u_r - corr - q_r*g;
      mf_s[lam] = mf_r;
      outp[((size_t)t*B_ + b)*L_ + lam] = mf_r;
    }
    barV();  // B4 (mf_s, z_s visible; fences this step's prefetches)
  }
}

extern "C" void kernel_launch(void* const* d_in, const int* in_sizes, int n_in,
                              void* d_out, int out_size, void* d_ws, size_t ws_size,
                              hipStream_t stream) {
  (void)in_sizes; (void)n_in; (void)out_size; (void)d_ws; (void)ws_size;
  nlf_kernel<<<dim3(B_), dim3(512), 0, stream>>>(
      (const float*)d_in[0], (const float*)d_in[1], (const float*)d_in[2],
      (const float*)d_in[3], (const float*)d_in[4], (const float*)d_in[5],
      (const float*)d_in[6], (const float*)d_in[7], (const float*)d_in[8],
      (const float*)d_in[9], (const float*)d_in[10], (float*)d_out);
}